// Round 1
// baseline (1499.774 us; speedup 1.0000x reference)
//
#include <hip/hip_runtime.h>
#include <hip/hip_bf16.h>

#define NB 4
#define LSEQ 2048
#define NROWS (NB * LSEQ)        // 8192
#define DMODEL 512
#define DINNER 1024
#define NSTATE 16
#define DTRANK 32
#define LN_EPS 1e-5f

typedef _Float16 f16;
typedef _Float16 f16x8 __attribute__((ext_vector_type(8)));
typedef float f32x4 __attribute__((ext_vector_type(4)));

// ---------------------------------------------------------------- utilities
__device__ inline float wave_sum(float v) {
#pragma unroll
    for (int off = 32; off; off >>= 1) v += __shfl_xor(v, off, 64);
    return v;
}

// ---------------------------------------------------------------- LN(x) -> f16
__global__ __launch_bounds__(256) void ln_x_to_f16(const float* __restrict__ x,
                                                   const float* __restrict__ w,
                                                   const float* __restrict__ b,
                                                   f16* __restrict__ out) {
    int row = blockIdx.x * 4 + (threadIdx.x >> 6);
    int lane = threadIdx.x & 63;
    const float* xr = x + (size_t)row * DMODEL + lane * 8;
    float vv[8];
    *(float4*)(vv) = *(const float4*)(xr);
    *(float4*)(vv + 4) = *(const float4*)(xr + 4);
    float s = 0.f, sq = 0.f;
#pragma unroll
    for (int j = 0; j < 8; ++j) { s += vv[j]; sq += vv[j] * vv[j]; }
    s = wave_sum(s); sq = wave_sum(sq);
    float mu = s * (1.f / DMODEL);
    float var = sq * (1.f / DMODEL) - mu * mu;
    float rstd = rsqrtf(var + LN_EPS);
    f16x8 o;
#pragma unroll
    for (int j = 0; j < 8; ++j) {
        int c = lane * 8 + j;
        o[j] = (f16)((vv[j] - mu) * rstd * w[c] + b[c]);
    }
    *(f16x8*)(out + (size_t)row * DMODEL + lane * 8) = o;
}

// ---------------------------------------------------------------- f32 -> f16 (with row pad)
__global__ void cvt_f16_pad(const float* __restrict__ in, f16* __restrict__ out,
                            int rows_in, int cols, int total_out) {
    int i = blockIdx.x * blockDim.x + threadIdx.x;
    int stride = gridDim.x * blockDim.x;
    for (; i < total_out; i += stride) {
        int r = i / cols;
        out[i] = (r < rows_in) ? (f16)in[i] : (f16)0.f;
    }
}

// ---------------------------------------------------------------- GEMM: C[M,N] = X[M,K] @ W[N,K]^T
// 128x128 tile, BK=32, 4 waves, each wave 64x64 (4x4 of 16x16x32 MFMA).
template <bool OUT_F16>
__global__ __launch_bounds__(256) void gemm_xwt(const f16* __restrict__ X,
                                                const f16* __restrict__ W,
                                                void* __restrict__ Out,
                                                int K, int ldc) {
    __shared__ f16 As[128 * 32];
    __shared__ f16 Bs[128 * 32];
    const int tid = threadIdx.x;
    const int lane = tid & 63;
    const int wv = tid >> 6;
    const int wr = wv >> 1, wc = wv & 1;
    const int rowbase = blockIdx.y * 128;
    const int colbase = blockIdx.x * 128;

    const f32x4 zero = {0.f, 0.f, 0.f, 0.f};
    f32x4 acc[4][4];
#pragma unroll
    for (int m = 0; m < 4; ++m)
#pragma unroll
        for (int n = 0; n < 4; ++n) acc[m][n] = zero;

    const int nk = K >> 5;
    for (int kt = 0; kt < nk; ++kt) {
        const int k0 = kt << 5;
#pragma unroll
        for (int it = 0; it < 2; ++it) {
            int id = it * 256 + tid;       // 0..511 -> 512 x 16B per tile
            int row = id >> 2;             // 4 x 16B per 32-elem row
            int k8 = (id & 3) << 3;        // f16 offset within row
            float4 va = *(const float4*)(X + (size_t)(rowbase + row) * K + k0 + k8);
            float4 vb = *(const float4*)(W + (size_t)(colbase + row) * K + k0 + k8);
            *(float4*)(As + row * 32 + k8) = va;
            *(float4*)(Bs + row * 32 + k8) = vb;
        }
        __syncthreads();
        f16x8 af[4], bf[4];
#pragma unroll
        for (int m = 0; m < 4; ++m)
            af[m] = *(const f16x8*)(As + (wr * 64 + m * 16 + (lane & 15)) * 32 + ((lane >> 4) << 3));
#pragma unroll
        for (int n = 0; n < 4; ++n)
            bf[n] = *(const f16x8*)(Bs + (wc * 64 + n * 16 + (lane & 15)) * 32 + ((lane >> 4) << 3));
#pragma unroll
        for (int m = 0; m < 4; ++m)
#pragma unroll
            for (int n = 0; n < 4; ++n)
                acc[m][n] = __builtin_amdgcn_mfma_f32_16x16x32_f16(af[m], bf[n], acc[m][n], 0, 0, 0);
        __syncthreads();
    }
#pragma unroll
    for (int m = 0; m < 4; ++m) {
        int r0 = rowbase + wr * 64 + m * 16 + ((lane >> 4) << 2);
#pragma unroll
        for (int n = 0; n < 4; ++n) {
            int c = colbase + wc * 64 + n * 16 + (lane & 15);
#pragma unroll
            for (int r = 0; r < 4; ++r) {
                float v = acc[m][n][r];
                if (OUT_F16) ((f16*)Out)[(size_t)(r0 + r) * ldc + c] = (f16)v;
                else         ((float*)Out)[(size_t)(r0 + r) * ldc + c] = v;
            }
        }
    }
}

// ---------------------------------------------------------------- causal depthwise conv + silu
__global__ void conv_silu(const f16* __restrict__ xz,   // (8192, 2048), xm = cols [0,1024)
                          const float* __restrict__ cw, // (1024,1,4)
                          const float* __restrict__ cb,
                          f16* __restrict__ out16, float* __restrict__ outf) {
    int i = blockIdx.x * blockDim.x + threadIdx.x;
    int stride = gridDim.x * blockDim.x;
    for (; i < NROWS * DINNER; i += stride) {
        int d = i & (DINNER - 1);
        int row = i >> 10;
        int t = row & (LSEQ - 1);
        float acc = cb[d];
#pragma unroll
        for (int j = 0; j < 4; ++j) {
            int tt = t - 3 + j;
            if (tt >= 0)
                acc += cw[d * 4 + j] * (float)xz[(size_t)(row - 3 + j) * (2 * DINNER) + d];
        }
        float sv = acc / (1.f + __expf(-acc));
        out16[i] = (f16)sv;
        outf[i] = sv;
    }
}

// ---------------------------------------------------------------- dt split (cols 0..31 of x_dbl, ld 128) -> f16
__global__ void dt_split(const float* __restrict__ xdbl, f16* __restrict__ dt16) {
    int i = blockIdx.x * blockDim.x + threadIdx.x;
    int stride = gridDim.x * blockDim.x;
    for (; i < NROWS * DTRANK; i += stride) {
        int r = i >> 5, c = i & 31;
        dt16[i] = (f16)xdbl[(size_t)r * 128 + c];
    }
}

// ---------------------------------------------------------------- softplus(v + bias), in-place
__global__ void softplus_bias(float* __restrict__ p, const float* __restrict__ bias) {
    int i = blockIdx.x * blockDim.x + threadIdx.x;
    int stride = gridDim.x * blockDim.x;
    for (; i < NROWS * DINNER; i += stride) {
        int d = i & (DINNER - 1);
        float v = p[i] + bias[d];
        p[i] = fmaxf(v, 0.f) + log1pf(__expf(-fabsf(v)));
    }
}

// ---------------------------------------------------------------- selective scan (serial over L)
__device__ inline void load16(float* dst, const float* src) {
    float4* d4 = (float4*)dst; const float4* s4 = (const float4*)src;
    d4[0] = s4[0]; d4[1] = s4[1]; d4[2] = s4[2]; d4[3] = s4[3];
}

__global__ __launch_bounds__(256) void scan_seq(const float* __restrict__ delta,
                                                const float* __restrict__ u,
                                                const float* __restrict__ xdbl, // (8192,128): B at 32, C at 48
                                                const float* __restrict__ A_log,
                                                const float* __restrict__ Dv,
                                                float* __restrict__ y) {
    int b = blockIdx.x >> 2;
    int d = ((blockIdx.x & 3) << 8) + threadIdx.x;
    float A[NSTATE];
#pragma unroll
    for (int n = 0; n < NSTATE; ++n) A[n] = -__expf(A_log[d * NSTATE + n]);
    float Dval = Dv[d];
    float h[NSTATE];
#pragma unroll
    for (int n = 0; n < NSTATE; ++n) h[n] = 0.f;

    size_t rbase = (size_t)b * LSEQ;
    float del = delta[rbase * DINNER + d];
    float uu = u[rbase * DINNER + d];
    float Bc[NSTATE], Cc[NSTATE];
    load16(Bc, xdbl + rbase * 128 + 32);
    load16(Cc, xdbl + rbase * 128 + 48);

    for (int t = 0; t < LSEQ; ++t) {
        // prefetch t+1 (clamped; last iter redundantly reloads t)
        size_t r = rbase + ((t < LSEQ - 1) ? t + 1 : t);
        float del_n = delta[r * DINNER + d];
        float uu_n = u[r * DINNER + d];
        float Bn[NSTATE], Cn[NSTATE];
        load16(Bn, xdbl + r * 128 + 32);
        load16(Cn, xdbl + r * 128 + 48);

        float du = del * uu;
        float yv = 0.f;
#pragma unroll
        for (int n = 0; n < NSTATE; ++n) {
            float dA = __expf(del * A[n]);
            h[n] = dA * h[n] + du * Bc[n];
            yv += h[n] * Cc[n];
        }
        y[(rbase + t) * DINNER + d] = yv + uu * Dval;

        del = del_n; uu = uu_n;
#pragma unroll
        for (int n = 0; n < NSTATE; ++n) { Bc[n] = Bn[n]; Cc[n] = Cn[n]; }
    }
}

// ---------------------------------------------------------------- y * silu(z) -> f16
__global__ void ymul_silu(const float* __restrict__ y, const f16* __restrict__ xz,
                          f16* __restrict__ y16) {
    int i = blockIdx.x * blockDim.x + threadIdx.x;
    int stride = gridDim.x * blockDim.x;
    for (; i < NROWS * DINNER; i += stride) {
        int d = i & (DINNER - 1);
        int row = i >> 10;
        float z = (float)xz[(size_t)row * (2 * DINNER) + DINNER + d];
        float s = z / (1.f + __expf(-z));
        y16[i] = (f16)(y[i] * s);
    }
}

// ---------------------------------------------------------------- output LNs
__global__ __launch_bounds__(256) void ln_match(const float* __restrict__ resid,
                                                const float* __restrict__ raw,
                                                const float* __restrict__ mb,
                                                const float* __restrict__ w,
                                                const float* __restrict__ b,
                                                float* __restrict__ out) {
    int row = blockIdx.x * 4 + (threadIdx.x >> 6);
    int lane = threadIdx.x & 63;
    float vv[8];
#pragma unroll
    for (int j = 0; j < 8; ++j) {
        int c = lane * 8 + j;
        vv[j] = resid[(size_t)row * DMODEL + c] + raw[(size_t)row * DMODEL + c] + mb[c];
    }
    float s = 0.f, sq = 0.f;
#pragma unroll
    for (int j = 0; j < 8; ++j) { s += vv[j]; sq += vv[j] * vv[j]; }
    s = wave_sum(s); sq = wave_sum(sq);
    float mu = s * (1.f / DMODEL);
    float rstd = rsqrtf(sq * (1.f / DMODEL) - mu * mu + LN_EPS);
    float ov[8];
#pragma unroll
    for (int j = 0; j < 8; ++j) {
        int c = lane * 8 + j;
        ov[j] = (vv[j] - mu) * rstd * w[c] + b[c];
    }
    float* op = out + (size_t)row * DMODEL + lane * 8;
    *(float4*)(op) = *(float4*)(ov);
    *(float4*)(op + 4) = *(float4*)(ov + 4);
}

__global__ __launch_bounds__(256) void ln_geom(const float* __restrict__ raw,
                                               const float* __restrict__ gb,
                                               const float* __restrict__ w,
                                               const float* __restrict__ b,
                                               float* __restrict__ out) {
    const int DG = 256;
    int row = blockIdx.x * 4 + (threadIdx.x >> 6);
    int lane = threadIdx.x & 63;
    float vv[4];
#pragma unroll
    for (int j = 0; j < 4; ++j) {
        int c = lane * 4 + j;
        vv[j] = raw[(size_t)row * DG + c] + gb[c];
    }
    float s = 0.f, sq = 0.f;
#pragma unroll
    for (int j = 0; j < 4; ++j) { s += vv[j]; sq += vv[j] * vv[j]; }
    s = wave_sum(s); sq = wave_sum(sq);
    float mu = s * (1.f / DG);
    float rstd = rsqrtf(sq * (1.f / DG) - mu * mu + LN_EPS);
    float ov[4];
#pragma unroll
    for (int j = 0; j < 4; ++j) {
        int c = lane * 4 + j;
        ov[j] = (vv[j] - mu) * rstd * w[c] + b[c];
    }
    *(float4*)(out + (size_t)row * DG + lane * 4) = *(float4*)(ov);
}

// ---------------------------------------------------------------- launcher
extern "C" void kernel_launch(void* const* d_in, const int* in_sizes, int n_in,
                              void* d_out, int out_size, void* d_ws, size_t ws_size,
                              hipStream_t stream) {
    const float* x         = (const float*)d_in[0];
    const float* norm_w    = (const float*)d_in[1];
    const float* norm_b    = (const float*)d_in[2];
    const float* in_proj_w = (const float*)d_in[3];
    const float* conv_w    = (const float*)d_in[4];
    const float* conv_b    = (const float*)d_in[5];
    const float* x_proj_w  = (const float*)d_in[6];
    const float* dt_proj_w = (const float*)d_in[7];
    const float* dt_proj_b = (const float*)d_in[8];
    const float* A_log     = (const float*)d_in[9];
    const float* Dvec      = (const float*)d_in[10];
    const float* mix_out_w = (const float*)d_in[11];
    const float* match_w   = (const float*)d_in[12];
    const float* match_b   = (const float*)d_in[13];
    const float* geom_w    = (const float*)d_in[14];
    const float* geom_b    = (const float*)d_in[15];
    const float* normm_w   = (const float*)d_in[16];
    const float* normm_b   = (const float*)d_in[17];
    const float* normg_w   = (const float*)d_in[18];
    const float* normg_b   = (const float*)d_in[19];

    char* ws = (char*)d_ws;
    // workspace layout (bytes)
    f16* h16    = (f16*)(ws + 0);            // 8 MB   (reused as hm16 later)
    f16* wip    = (f16*)(ws + 8388608);      // in_proj  2048x512
    f16* wxp    = (f16*)(ws + 10485760);     // x_proj   128x1024 (padded)
    f16* wdt    = (f16*)(ws + 10747904);     // dt_proj  1024x32
    f16* wmo    = (f16*)(ws + 10813440);     // mix_out  512x1024
    f16* wma    = (f16*)(ws + 11862016);     // match    512x512
    f16* wge    = (f16*)(ws + 12386304);     // geom     256x512
    f16* xz16   = (f16*)(ws + 12648448);     // 8192x2048 f16, 32 MB
    f16* xmc16  = (f16*)(ws + 46202880);     // 8192x1024 f16, 16 MB (reused as y16)
    float* xmcf = (float*)(ws + 62980096);   // 8192x1024 f32, 32 MB (reused: traw 16MB + graw 8MB)
    float* xdbl = (float*)(ws + 96534528);   // 8192x128 f32, 4 MB
    f16* dt16   = (f16*)(ws + 100728832);    // 8192x32 f16
    float* delta = (float*)(ws + 101253120); // 8192x1024 f32, 32 MB (y written in-place)

    f16* hm16 = h16;
    f16* y16 = xmc16;
    float* traw = xmcf;
    float* graw = xmcf + (size_t)NROWS * DMODEL;
    float* out0 = (float*)d_out;
    float* out1 = out0 + (size_t)NROWS * DMODEL;

    // 1. LayerNorm(x) -> h16
    ln_x_to_f16<<<NROWS / 4, 256, 0, stream>>>(x, norm_w, norm_b, h16);
    // 2. weight conversions (x_proj padded 64->128 rows)
    cvt_f16_pad<<<256, 256, 0, stream>>>(in_proj_w, wip, 2048, 512, 2048 * 512);
    cvt_f16_pad<<<256, 256, 0, stream>>>(x_proj_w, wxp, 64, 1024, 128 * 1024);
    cvt_f16_pad<<<256, 256, 0, stream>>>(dt_proj_w, wdt, 1024, 32, 1024 * 32);
    cvt_f16_pad<<<256, 256, 0, stream>>>(mix_out_w, wmo, 512, 1024, 512 * 1024);
    cvt_f16_pad<<<256, 256, 0, stream>>>(match_w, wma, 512, 512, 512 * 512);
    cvt_f16_pad<<<256, 256, 0, stream>>>(geom_w, wge, 256, 512, 256 * 512);
    // 3. xz = h @ in_proj^T  (f16 out)
    gemm_xwt<true><<<dim3(2048 / 128, NROWS / 128), 256, 0, stream>>>(h16, wip, xz16, 512, 2048);
    // 4. conv + silu
    conv_silu<<<2048, 256, 0, stream>>>(xz16, conv_w, conv_b, xmc16, xmcf);
    // 5. x_dbl = xm @ x_proj^T (f32, ld 128)
    gemm_xwt<false><<<dim3(1, NROWS / 128), 256, 0, stream>>>(xmc16, wxp, xdbl, 1024, 128);
    // 6. dt -> f16
    dt_split<<<256, 256, 0, stream>>>(xdbl, dt16);
    // 7. delta_raw = dt @ dt_proj^T (f32)
    gemm_xwt<false><<<dim3(1024 / 128, NROWS / 128), 256, 0, stream>>>(dt16, wdt, delta, 32, 1024);
    // 8. delta = softplus(delta_raw + b)
    softplus_bias<<<2048, 256, 0, stream>>>(delta, dt_proj_b);
    // 9. selective scan (y overwrites delta)
    scan_seq<<<16, 256, 0, stream>>>(delta, xmcf, xdbl, A_log, Dvec, delta);
    // 10. y16 = y * silu(z)
    ymul_silu<<<2048, 256, 0, stream>>>(delta, xz16, y16);
    // 11. hm = y @ mix_out^T (f16)
    gemm_xwt<true><<<dim3(512 / 128, NROWS / 128), 256, 0, stream>>>(y16, wmo, hm16, 1024, 512);
    // 12. match / geom GEMMs (f32 raw)
    gemm_xwt<false><<<dim3(512 / 128, NROWS / 128), 256, 0, stream>>>(hm16, wma, traw, 512, 512);
    gemm_xwt<false><<<dim3(256 / 128, NROWS / 128), 256, 0, stream>>>(hm16, wge, graw, 512, 256);
    // 13. output layernorms
    ln_match<<<NROWS / 4, 256, 0, stream>>>(x, traw, match_b, normm_w, normm_b, out0);
    ln_geom<<<NROWS / 4, 256, 0, stream>>>(graw, geom_b, normg_w, normg_b, out1);
}

// Round 2
// 421.266 us; speedup vs baseline: 3.5602x; 3.5602x over previous
//
#include <hip/hip_runtime.h>
#include <hip/hip_bf16.h>

#define NB 4
#define LSEQ 2048
#define NROWS (NB * LSEQ)        // 8192
#define DMODEL 512
#define DINNER 1024
#define NSTATE 16
#define DTRANK 32
#define LN_EPS 1e-5f

#define NCHUNK 32
#define TCHUNK 64               // NCHUNK * TCHUNK == LSEQ

typedef _Float16 f16;
typedef _Float16 f16x8 __attribute__((ext_vector_type(8)));
typedef float f32x4 __attribute__((ext_vector_type(4)));

// ---------------------------------------------------------------- utilities
__device__ inline float wave_sum(float v) {
#pragma unroll
    for (int off = 32; off; off >>= 1) v += __shfl_xor(v, off, 64);
    return v;
}

// ---------------------------------------------------------------- LN(x) -> f16
__global__ __launch_bounds__(256) void ln_x_to_f16(const float* __restrict__ x,
                                                   const float* __restrict__ w,
                                                   const float* __restrict__ b,
                                                   f16* __restrict__ out) {
    int row = blockIdx.x * 4 + (threadIdx.x >> 6);
    int lane = threadIdx.x & 63;
    const float* xr = x + (size_t)row * DMODEL + lane * 8;
    float vv[8];
    *(float4*)(vv) = *(const float4*)(xr);
    *(float4*)(vv + 4) = *(const float4*)(xr + 4);
    float s = 0.f, sq = 0.f;
#pragma unroll
    for (int j = 0; j < 8; ++j) { s += vv[j]; sq += vv[j] * vv[j]; }
    s = wave_sum(s); sq = wave_sum(sq);
    float mu = s * (1.f / DMODEL);
    float var = sq * (1.f / DMODEL) - mu * mu;
    float rstd = rsqrtf(var + LN_EPS);
    f16x8 o;
#pragma unroll
    for (int j = 0; j < 8; ++j) {
        int c = lane * 8 + j;
        o[j] = (f16)((vv[j] - mu) * rstd * w[c] + b[c]);
    }
    *(f16x8*)(out + (size_t)row * DMODEL + lane * 8) = o;
}

// ---------------------------------------------------------------- f32 -> f16 (with row pad)
__global__ void cvt_f16_pad(const float* __restrict__ in, f16* __restrict__ out,
                            int rows_in, int cols, int total_out) {
    int i = blockIdx.x * blockDim.x + threadIdx.x;
    int stride = gridDim.x * blockDim.x;
    for (; i < total_out; i += stride) {
        int r = i / cols;
        out[i] = (r < rows_in) ? (f16)in[i] : (f16)0.f;
    }
}

// ---------------------------------------------------------------- GEMM: C[M,N] = X[M,K] @ W[N,K]^T
template <bool OUT_F16>
__global__ __launch_bounds__(256) void gemm_xwt(const f16* __restrict__ X,
                                                const f16* __restrict__ W,
                                                void* __restrict__ Out,
                                                int K, int ldc) {
    __shared__ f16 As[128 * 32];
    __shared__ f16 Bs[128 * 32];
    const int tid = threadIdx.x;
    const int lane = tid & 63;
    const int wv = tid >> 6;
    const int wr = wv >> 1, wc = wv & 1;
    const int rowbase = blockIdx.y * 128;
    const int colbase = blockIdx.x * 128;

    const f32x4 zero = {0.f, 0.f, 0.f, 0.f};
    f32x4 acc[4][4];
#pragma unroll
    for (int m = 0; m < 4; ++m)
#pragma unroll
        for (int n = 0; n < 4; ++n) acc[m][n] = zero;

    const int nk = K >> 5;
    for (int kt = 0; kt < nk; ++kt) {
        const int k0 = kt << 5;
#pragma unroll
        for (int it = 0; it < 2; ++it) {
            int id = it * 256 + tid;
            int row = id >> 2;
            int k8 = (id & 3) << 3;
            float4 va = *(const float4*)(X + (size_t)(rowbase + row) * K + k0 + k8);
            float4 vb = *(const float4*)(W + (size_t)(colbase + row) * K + k0 + k8);
            *(float4*)(As + row * 32 + k8) = va;
            *(float4*)(Bs + row * 32 + k8) = vb;
        }
        __syncthreads();
        f16x8 af[4], bf[4];
#pragma unroll
        for (int m = 0; m < 4; ++m)
            af[m] = *(const f16x8*)(As + (wr * 64 + m * 16 + (lane & 15)) * 32 + ((lane >> 4) << 3));
#pragma unroll
        for (int n = 0; n < 4; ++n)
            bf[n] = *(const f16x8*)(Bs + (wc * 64 + n * 16 + (lane & 15)) * 32 + ((lane >> 4) << 3));
#pragma unroll
        for (int m = 0; m < 4; ++m)
#pragma unroll
            for (int n = 0; n < 4; ++n)
                acc[m][n] = __builtin_amdgcn_mfma_f32_16x16x32_f16(af[m], bf[n], acc[m][n], 0, 0, 0);
        __syncthreads();
    }
#pragma unroll
    for (int m = 0; m < 4; ++m) {
        int r0 = rowbase + wr * 64 + m * 16 + ((lane >> 4) << 2);
#pragma unroll
        for (int n = 0; n < 4; ++n) {
            int c = colbase + wc * 64 + n * 16 + (lane & 15);
#pragma unroll
            for (int r = 0; r < 4; ++r) {
                float v = acc[m][n][r];
                if (OUT_F16) ((f16*)Out)[(size_t)(r0 + r) * ldc + c] = (f16)v;
                else         ((float*)Out)[(size_t)(r0 + r) * ldc + c] = v;
            }
        }
    }
}

// ---------------------------------------------------------------- causal depthwise conv + silu
__global__ void conv_silu(const f16* __restrict__ xz,
                          const float* __restrict__ cw,
                          const float* __restrict__ cb,
                          f16* __restrict__ out16, float* __restrict__ outf) {
    int i = blockIdx.x * blockDim.x + threadIdx.x;
    int stride = gridDim.x * blockDim.x;
    for (; i < NROWS * DINNER; i += stride) {
        int d = i & (DINNER - 1);
        int row = i >> 10;
        int t = row & (LSEQ - 1);
        float acc = cb[d];
#pragma unroll
        for (int j = 0; j < 4; ++j) {
            int tt = t - 3 + j;
            if (tt >= 0)
                acc += cw[d * 4 + j] * (float)xz[(size_t)(row - 3 + j) * (2 * DINNER) + d];
        }
        float sv = acc / (1.f + __expf(-acc));
        out16[i] = (f16)sv;
        outf[i] = sv;
    }
}

// ---------------------------------------------------------------- dt split -> f16
__global__ void dt_split(const float* __restrict__ xdbl, f16* __restrict__ dt16) {
    int i = blockIdx.x * blockDim.x + threadIdx.x;
    int stride = gridDim.x * blockDim.x;
    for (; i < NROWS * DTRANK; i += stride) {
        int r = i >> 5, c = i & 31;
        dt16[i] = (f16)xdbl[(size_t)r * 128 + c];
    }
}

// ---------------------------------------------------------------- softplus(v + bias), in-place
__global__ void softplus_bias(float* __restrict__ p, const float* __restrict__ bias) {
    int i = blockIdx.x * blockDim.x + threadIdx.x;
    int stride = gridDim.x * blockDim.x;
    for (; i < NROWS * DINNER; i += stride) {
        int d = i & (DINNER - 1);
        float v = p[i] + bias[d];
        p[i] = fmaxf(v, 0.f) + log1pf(__expf(-fabsf(v)));
    }
}

// ---------------------------------------------------------------- chunked scan
__device__ inline void load16(float* dst, const float* src) {
    float4* d4 = (float4*)dst; const float4* s4 = (const float4*)src;
    d4[0] = s4[0]; d4[1] = s4[1]; d4[2] = s4[2]; d4[3] = s4[3];
}

// pass 1: per (b, chunk, d) local scan from h=0; store end state + sum(delta)
__global__ __launch_bounds__(256) void scan_pass1(const float* __restrict__ delta,
                                                  const float* __restrict__ u,
                                                  const float* __restrict__ xdbl,
                                                  const float* __restrict__ A_log,
                                                  float* __restrict__ hloc,
                                                  float* __restrict__ sumdelta) {
    int blk = blockIdx.x;
    int dg = blk & 3;
    int c = (blk >> 2) & (NCHUNK - 1);
    int b = blk >> 7;
    int d = dg * 256 + threadIdx.x;

    float A[NSTATE];
#pragma unroll
    for (int n = 0; n < NSTATE; ++n) A[n] = -__expf(A_log[d * NSTATE + n]);
    float h[NSTATE];
#pragma unroll
    for (int n = 0; n < NSTATE; ++n) h[n] = 0.f;

    size_t rbase = (size_t)b * LSEQ + c * TCHUNK;
    float sd = 0.f;
    for (int t = 0; t < TCHUNK; ++t) {
        size_t r = rbase + t;
        float del = delta[r * DINNER + d];
        float uu = u[r * DINNER + d];
        float Bv[NSTATE];
        load16(Bv, xdbl + r * 128 + 32);
        sd += del;
        float du = del * uu;
#pragma unroll
        for (int n = 0; n < NSTATE; ++n)
            h[n] = __expf(del * A[n]) * h[n] + du * Bv[n];
    }
    size_t idx = ((size_t)(b * NCHUNK + c) * DINNER + d);
#pragma unroll
    for (int q = 0; q < 4; ++q)
        *(float4*)(hloc + idx * NSTATE + q * 4) = *(float4*)(h + q * 4);
    sumdelta[idx] = sd;
}

// combine: one thread per (b,d,n); serial over chunks; h0[c] = state before chunk c
__global__ __launch_bounds__(256) void scan_combine(const float* __restrict__ hloc,
                                                    const float* __restrict__ sumdelta,
                                                    const float* __restrict__ A_log,
                                                    float* __restrict__ h0) {
    int g = blockIdx.x * 256 + threadIdx.x;       // 0 .. B*D*N-1
    int n = g & 15;
    int d = (g >> 4) & (DINNER - 1);
    int b = g >> 14;
    float A = -__expf(A_log[d * NSTATE + n]);
    float h = 0.f;
    for (int c = 0; c < NCHUNK; ++c) {
        size_t idx = ((size_t)(b * NCHUNK + c) * DINNER + d);
        h0[idx * NSTATE + n] = h;
        float sd = sumdelta[idx];
        h = __expf(A * sd) * h + hloc[idx * NSTATE + n];
    }
}

// pass 2: rerun scan with true h0, compute y, fuse *silu(z), write f16
__global__ __launch_bounds__(256) void scan_pass2(const float* __restrict__ delta,
                                                  const float* __restrict__ u,
                                                  const float* __restrict__ xdbl,
                                                  const float* __restrict__ A_log,
                                                  const float* __restrict__ Dv,
                                                  const float* __restrict__ h0,
                                                  const f16* __restrict__ xz,
                                                  f16* __restrict__ y16) {
    int blk = blockIdx.x;
    int dg = blk & 3;
    int c = (blk >> 2) & (NCHUNK - 1);
    int b = blk >> 7;
    int d = dg * 256 + threadIdx.x;

    float A[NSTATE];
#pragma unroll
    for (int n = 0; n < NSTATE; ++n) A[n] = -__expf(A_log[d * NSTATE + n]);
    float Dval = Dv[d];
    float h[NSTATE];
    size_t idx = ((size_t)(b * NCHUNK + c) * DINNER + d);
#pragma unroll
    for (int q = 0; q < 4; ++q)
        *(float4*)(h + q * 4) = *(const float4*)(h0 + idx * NSTATE + q * 4);

    size_t rbase = (size_t)b * LSEQ + c * TCHUNK;
    for (int t = 0; t < TCHUNK; ++t) {
        size_t r = rbase + t;
        float del = delta[r * DINNER + d];
        float uu = u[r * DINNER + d];
        float Bv[NSTATE], Cv[NSTATE];
        load16(Bv, xdbl + r * 128 + 32);
        load16(Cv, xdbl + r * 128 + 48);
        float du = del * uu;
        float yv = 0.f;
#pragma unroll
        for (int n = 0; n < NSTATE; ++n) {
            h[n] = __expf(del * A[n]) * h[n] + du * Bv[n];
            yv += h[n] * Cv[n];
        }
        yv += uu * Dval;
        float z = (float)xz[r * (2 * DINNER) + DINNER + d];
        float sz = z / (1.f + __expf(-z));
        y16[r * DINNER + d] = (f16)(yv * sz);
    }
}

// ---------------------------------------------------------------- output LNs
__global__ __launch_bounds__(256) void ln_match(const float* __restrict__ resid,
                                                const float* __restrict__ raw,
                                                const float* __restrict__ mb,
                                                const float* __restrict__ w,
                                                const float* __restrict__ b,
                                                float* __restrict__ out) {
    int row = blockIdx.x * 4 + (threadIdx.x >> 6);
    int lane = threadIdx.x & 63;
    float vv[8];
#pragma unroll
    for (int j = 0; j < 8; ++j) {
        int c = lane * 8 + j;
        vv[j] = resid[(size_t)row * DMODEL + c] + raw[(size_t)row * DMODEL + c] + mb[c];
    }
    float s = 0.f, sq = 0.f;
#pragma unroll
    for (int j = 0; j < 8; ++j) { s += vv[j]; sq += vv[j] * vv[j]; }
    s = wave_sum(s); sq = wave_sum(sq);
    float mu = s * (1.f / DMODEL);
    float rstd = rsqrtf(sq * (1.f / DMODEL) - mu * mu + LN_EPS);
    float ov[8];
#pragma unroll
    for (int j = 0; j < 8; ++j) {
        int c = lane * 8 + j;
        ov[j] = (vv[j] - mu) * rstd * w[c] + b[c];
    }
    float* op = out + (size_t)row * DMODEL + lane * 8;
    *(float4*)(op) = *(float4*)(ov);
    *(float4*)(op + 4) = *(float4*)(ov + 4);
}

__global__ __launch_bounds__(256) void ln_geom(const float* __restrict__ raw,
                                               const float* __restrict__ gb,
                                               const float* __restrict__ w,
                                               const float* __restrict__ b,
                                               float* __restrict__ out) {
    const int DG = 256;
    int row = blockIdx.x * 4 + (threadIdx.x >> 6);
    int lane = threadIdx.x & 63;
    float vv[4];
#pragma unroll
    for (int j = 0; j < 4; ++j) {
        int c = lane * 4 + j;
        vv[j] = raw[(size_t)row * DG + c] + gb[c];
    }
    float s = 0.f, sq = 0.f;
#pragma unroll
    for (int j = 0; j < 4; ++j) { s += vv[j]; sq += vv[j] * vv[j]; }
    s = wave_sum(s); sq = wave_sum(sq);
    float mu = s * (1.f / DG);
    float rstd = rsqrtf(sq * (1.f / DG) - mu * mu + LN_EPS);
    float ov[4];
#pragma unroll
    for (int j = 0; j < 4; ++j) {
        int c = lane * 4 + j;
        ov[j] = (vv[j] - mu) * rstd * w[c] + b[c];
    }
    *(float4*)(out + (size_t)row * DG + lane * 4) = *(float4*)(ov);
}

// ---------------------------------------------------------------- launcher
extern "C" void kernel_launch(void* const* d_in, const int* in_sizes, int n_in,
                              void* d_out, int out_size, void* d_ws, size_t ws_size,
                              hipStream_t stream) {
    const float* x         = (const float*)d_in[0];
    const float* norm_w    = (const float*)d_in[1];
    const float* norm_b    = (const float*)d_in[2];
    const float* in_proj_w = (const float*)d_in[3];
    const float* conv_w    = (const float*)d_in[4];
    const float* conv_b    = (const float*)d_in[5];
    const float* x_proj_w  = (const float*)d_in[6];
    const float* dt_proj_w = (const float*)d_in[7];
    const float* dt_proj_b = (const float*)d_in[8];
    const float* A_log     = (const float*)d_in[9];
    const float* Dvec      = (const float*)d_in[10];
    const float* mix_out_w = (const float*)d_in[11];
    const float* match_w   = (const float*)d_in[12];
    const float* match_b   = (const float*)d_in[13];
    const float* geom_w    = (const float*)d_in[14];
    const float* geom_b    = (const float*)d_in[15];
    const float* normm_w   = (const float*)d_in[16];
    const float* normm_b   = (const float*)d_in[17];
    const float* normg_w   = (const float*)d_in[18];
    const float* normg_b   = (const float*)d_in[19];

    char* ws = (char*)d_ws;
    // workspace layout (bytes) — total 134.8 MB (same as round 0)
    f16* h16    = (f16*)(ws + 0);            // 8 MB  (reused: h0 after combine, hm16 after pass2)
    f16* wip    = (f16*)(ws + 8388608);
    f16* wxp    = (f16*)(ws + 10485760);
    f16* wdt    = (f16*)(ws + 10747904);
    f16* wmo    = (f16*)(ws + 10813440);
    f16* wma    = (f16*)(ws + 11862016);
    f16* wge    = (f16*)(ws + 12386304);
    f16* xz16   = (f16*)(ws + 12648448);     // 32 MB
    f16* xmc16  = (f16*)(ws + 46202880);     // 16 MB (dead after x_proj GEMM; reused: hloc, then y16)
    float* xmcf = (float*)(ws + 62980096);   // 32 MB (u; reused: traw+graw after pass2)
    float* xdbl = (float*)(ws + 96534528);   // 4 MB
    f16* dt16   = (f16*)(ws + 100728832);    // 512 KB (dead after dt GEMM; reused: sumdelta)
    float* delta = (float*)(ws + 101253120); // 32 MB

    // scan scratch (aliased over dead regions)
    float* hloc     = (float*)xmc16;         // 8 MB  (B*NCHUNK*DINNER*NSTATE*4)
    float* sumdelta = (float*)dt16;          // 512 KB
    float* h0       = (float*)h16;           // 8 MB

    f16* hm16 = h16;
    f16* y16 = xmc16;
    float* traw = xmcf;
    float* graw = xmcf + (size_t)NROWS * DMODEL;
    float* out0 = (float*)d_out;
    float* out1 = out0 + (size_t)NROWS * DMODEL;

    // 1. LayerNorm(x) -> h16
    ln_x_to_f16<<<NROWS / 4, 256, 0, stream>>>(x, norm_w, norm_b, h16);
    // 2. weight conversions
    cvt_f16_pad<<<256, 256, 0, stream>>>(in_proj_w, wip, 2048, 512, 2048 * 512);
    cvt_f16_pad<<<256, 256, 0, stream>>>(x_proj_w, wxp, 64, 1024, 128 * 1024);
    cvt_f16_pad<<<256, 256, 0, stream>>>(dt_proj_w, wdt, 1024, 32, 1024 * 32);
    cvt_f16_pad<<<256, 256, 0, stream>>>(mix_out_w, wmo, 512, 1024, 512 * 1024);
    cvt_f16_pad<<<256, 256, 0, stream>>>(match_w, wma, 512, 512, 512 * 512);
    cvt_f16_pad<<<256, 256, 0, stream>>>(geom_w, wge, 256, 512, 256 * 512);
    // 3. xz = h @ in_proj^T
    gemm_xwt<true><<<dim3(2048 / 128, NROWS / 128), 256, 0, stream>>>(h16, wip, xz16, 512, 2048);
    // 4. conv + silu
    conv_silu<<<2048, 256, 0, stream>>>(xz16, conv_w, conv_b, xmc16, xmcf);
    // 5. x_dbl = xm @ x_proj^T
    gemm_xwt<false><<<dim3(1, NROWS / 128), 256, 0, stream>>>(xmc16, wxp, xdbl, 1024, 128);
    // 6. dt -> f16
    dt_split<<<256, 256, 0, stream>>>(xdbl, dt16);
    // 7. delta_raw = dt @ dt_proj^T
    gemm_xwt<false><<<dim3(1024 / 128, NROWS / 128), 256, 0, stream>>>(dt16, wdt, delta, 32, 1024);
    // 8. delta = softplus(delta_raw + b)
    softplus_bias<<<2048, 256, 0, stream>>>(delta, dt_proj_b);
    // 9. chunked selective scan (fuses y*silu(z) -> y16)
    scan_pass1<<<NB * NCHUNK * 4, 256, 0, stream>>>(delta, xmcf, xdbl, A_log, hloc, sumdelta);
    scan_combine<<<NB * DINNER * NSTATE / 256, 256, 0, stream>>>(hloc, sumdelta, A_log, h0);
    scan_pass2<<<NB * NCHUNK * 4, 256, 0, stream>>>(delta, xmcf, xdbl, A_log, Dvec, h0, xz16, y16);
    // 10. hm = y @ mix_out^T
    gemm_xwt<true><<<dim3(512 / 128, NROWS / 128), 256, 0, stream>>>(y16, wmo, hm16, 1024, 512);
    // 11. match / geom GEMMs
    gemm_xwt<false><<<dim3(512 / 128, NROWS / 128), 256, 0, stream>>>(hm16, wma, traw, 512, 512);
    gemm_xwt<false><<<dim3(256 / 128, NROWS / 128), 256, 0, stream>>>(hm16, wge, graw, 512, 256);
    // 12. output layernorms
    ln_match<<<NROWS / 4, 256, 0, stream>>>(x, traw, match_b, normm_w, normm_b, out0);
    ln_geom<<<NROWS / 4, 256, 0, stream>>>(graw, geom_b, normg_w, normg_b, out1);
}

// Round 3
// 380.833 us; speedup vs baseline: 3.9381x; 1.1062x over previous
//
#include <hip/hip_runtime.h>
#include <hip/hip_bf16.h>

#define NB 4
#define LSEQ 2048
#define NROWS (NB * LSEQ)        // 8192
#define DMODEL 512
#define DINNER 1024
#define NSTATE 16
#define DTRANK 32
#define LN_EPS 1e-5f

#define NCHUNK 64
#define TCHUNK 32               // NCHUNK * TCHUNK == LSEQ

typedef _Float16 f16;
typedef _Float16 f16x8 __attribute__((ext_vector_type(8)));
typedef float f32x4 __attribute__((ext_vector_type(4)));

// ---------------------------------------------------------------- utilities
__device__ inline float wave_sum(float v) {
#pragma unroll
    for (int off = 32; off; off >>= 1) v += __shfl_xor(v, off, 64);
    return v;
}

__device__ inline void load16(float* dst, const float* src) {
    float4* d4 = (float4*)dst; const float4* s4 = (const float4*)src;
    d4[0] = s4[0]; d4[1] = s4[1]; d4[2] = s4[2]; d4[3] = s4[3];
}

// ---------------------------------------------------------------- LN(x) -> f16
__global__ __launch_bounds__(256) void ln_x_to_f16(const float* __restrict__ x,
                                                   const float* __restrict__ w,
                                                   const float* __restrict__ b,
                                                   f16* __restrict__ out) {
    int row = blockIdx.x * 4 + (threadIdx.x >> 6);
    int lane = threadIdx.x & 63;
    const float* xr = x + (size_t)row * DMODEL + lane * 8;
    float vv[8];
    *(float4*)(vv) = *(const float4*)(xr);
    *(float4*)(vv + 4) = *(const float4*)(xr + 4);
    float s = 0.f, sq = 0.f;
#pragma unroll
    for (int j = 0; j < 8; ++j) { s += vv[j]; sq += vv[j] * vv[j]; }
    s = wave_sum(s); sq = wave_sum(sq);
    float mu = s * (1.f / DMODEL);
    float rstd = rsqrtf(sq * (1.f / DMODEL) - mu * mu + LN_EPS);
    f16x8 o;
#pragma unroll
    for (int j = 0; j < 8; ++j) {
        int c = lane * 8 + j;
        o[j] = (f16)((vv[j] - mu) * rstd * w[c] + b[c]);
    }
    *(f16x8*)(out + (size_t)row * DMODEL + lane * 8) = o;
}

// ---------------------------------------------------------------- all weight conversions, one kernel
// outputs are contiguous in ws starting at wip; x_proj rows 64..127 zero-padded
__global__ void cvt_weights(const float* __restrict__ ip, const float* __restrict__ xp,
                            const float* __restrict__ dt, const float* __restrict__ mo,
                            const float* __restrict__ ma, const float* __restrict__ ge,
                            f16* __restrict__ out) {
    int i = blockIdx.x * 256 + threadIdx.x;
    int stride = gridDim.x * 256;
    for (; i < 2129920; i += stride) {
        float v;
        if (i < 1048576) v = ip[i];
        else if (i < 1179648) { int j = i - 1048576; v = (j < 65536) ? xp[j] : 0.f; }
        else if (i < 1212416) v = dt[i - 1179648];
        else if (i < 1736704) v = mo[i - 1212416];
        else if (i < 1998848) v = ma[i - 1736704];
        else v = ge[i - 1998848];
        out[i] = (f16)v;
    }
}

// ---------------------------------------------------------------- GEMM: C[M,N] = X[M,K] @ W[N,K]^T
// 128x128 tile, BK=32, 4 waves; global_load_lds width-16 staging (m97 structure).
// MODE 0: f32 out | 1: f16 out | 2: f32 softplus(v+bias[col]) | 3: f32 out(ld128) + f16 aux for col<32
template <int MODE>
__global__ __launch_bounds__(256) void gemm_xwt(const f16* __restrict__ X,
                                                const f16* __restrict__ W,
                                                void* __restrict__ Out,
                                                int K, int ldc,
                                                const float* __restrict__ bias,
                                                f16* __restrict__ aux) {
    __shared__ f16 As[128 * 32];
    __shared__ f16 Bs[128 * 32];
    const int tid = threadIdx.x;
    const int lane = tid & 63;
    const int wv = tid >> 6;
    const int wr = wv >> 1, wc = wv & 1;
    const int rowbase = blockIdx.y * 128;
    const int colbase = blockIdx.x * 128;

    const f32x4 zero = {0.f, 0.f, 0.f, 0.f};
    f32x4 acc[4][4];
#pragma unroll
    for (int m = 0; m < 4; ++m)
#pragma unroll
        for (int n = 0; n < 4; ++n) acc[m][n] = zero;

    const int nk = K >> 5;
    for (int kt = 0; kt < nk; ++kt) {
        const int k0 = kt << 5;
#pragma unroll
        for (int it = 0; it < 2; ++it) {
            int id = it * 256 + wv * 64 + lane;     // 0..511
            int row = id >> 2;
            int k8 = (id & 3) << 3;
            const f16* ga = X + (size_t)(rowbase + row) * K + k0 + k8;
            const f16* gb = W + (size_t)(colbase + row) * K + k0 + k8;
            // LDS dest: wave-uniform base, lanes land at base + lane*16B (linear == row-major [128][32])
            __builtin_amdgcn_global_load_lds(
                (const __attribute__((address_space(1))) void*)ga,
                (__attribute__((address_space(3))) void*)(As + (it * 256 + wv * 64) * 8), 16, 0, 0);
            __builtin_amdgcn_global_load_lds(
                (const __attribute__((address_space(1))) void*)gb,
                (__attribute__((address_space(3))) void*)(Bs + (it * 256 + wv * 64) * 8), 16, 0, 0);
        }
        __syncthreads();
        f16x8 af[4], bf[4];
#pragma unroll
        for (int m = 0; m < 4; ++m)
            af[m] = *(const f16x8*)(As + (wr * 64 + m * 16 + (lane & 15)) * 32 + ((lane >> 4) << 3));
#pragma unroll
        for (int n = 0; n < 4; ++n)
            bf[n] = *(const f16x8*)(Bs + (wc * 64 + n * 16 + (lane & 15)) * 32 + ((lane >> 4) << 3));
#pragma unroll
        for (int m = 0; m < 4; ++m)
#pragma unroll
            for (int n = 0; n < 4; ++n)
                acc[m][n] = __builtin_amdgcn_mfma_f32_16x16x32_f16(af[m], bf[n], acc[m][n], 0, 0, 0);
        __syncthreads();
    }
#pragma unroll
    for (int m = 0; m < 4; ++m) {
        int r0 = rowbase + wr * 64 + m * 16 + ((lane >> 4) << 2);
#pragma unroll
        for (int n = 0; n < 4; ++n) {
            int c = colbase + wc * 64 + n * 16 + (lane & 15);
#pragma unroll
            for (int r = 0; r < 4; ++r) {
                float v = acc[m][n][r];
                size_t o = (size_t)(r0 + r) * ldc + c;
                if (MODE == 1) {
                    ((f16*)Out)[o] = (f16)v;
                } else if (MODE == 2) {
                    float t = v + bias[c];
                    ((float*)Out)[o] = fmaxf(t, 0.f) + log1pf(__expf(-fabsf(t)));
                } else if (MODE == 3) {
                    ((float*)Out)[o] = v;
                    if (c < DTRANK) aux[(size_t)(r0 + r) * DTRANK + c] = (f16)v;
                } else {
                    ((float*)Out)[o] = v;
                }
            }
        }
    }
}

// ---------------------------------------------------------------- causal depthwise conv + silu
__global__ void conv_silu(const f16* __restrict__ xz,
                          const float* __restrict__ cw,
                          const float* __restrict__ cb,
                          f16* __restrict__ out16, float* __restrict__ outf) {
    int i = blockIdx.x * blockDim.x + threadIdx.x;
    int stride = gridDim.x * blockDim.x;
    for (; i < NROWS * DINNER; i += stride) {
        int d = i & (DINNER - 1);
        int row = i >> 10;
        int t = row & (LSEQ - 1);
        float acc = cb[d];
#pragma unroll
        for (int j = 0; j < 4; ++j) {
            int tt = t - 3 + j;
            if (tt >= 0)
                acc += cw[d * 4 + j] * (float)xz[(size_t)(row - 3 + j) * (2 * DINNER) + d];
        }
        float sv = acc / (1.f + __expf(-acc));
        out16[i] = (f16)sv;
        outf[i] = sv;
    }
}

// ---------------------------------------------------------------- chunked scan
// pass 1: per (b, chunk, d) local scan from h=0; store end state + sum(delta)
__global__ __launch_bounds__(256) void scan_pass1(const float* __restrict__ delta,
                                                  const float* __restrict__ u,
                                                  const float* __restrict__ xdbl,
                                                  const float* __restrict__ A_log,
                                                  float* __restrict__ hloc,
                                                  float* __restrict__ sumdelta) {
    int blk = blockIdx.x;
    int dg = blk & 3;
    int c = (blk >> 2) & (NCHUNK - 1);
    int b = blk >> 8;                      // NCHUNK*4 = 256 blocks per b
    int d = dg * 256 + threadIdx.x;

    float A[NSTATE];
#pragma unroll
    for (int n = 0; n < NSTATE; ++n) A[n] = -__expf(A_log[d * NSTATE + n]);
    float h[NSTATE];
#pragma unroll
    for (int n = 0; n < NSTATE; ++n) h[n] = 0.f;

    size_t rbase = (size_t)b * LSEQ + (size_t)c * TCHUNK;
    const float* dp = delta + rbase * DINNER + d;
    const float* up = u + rbase * DINNER + d;
    const float* xp = xdbl + rbase * 128 + 32;

    float del = dp[0], uu = up[0];
    float Bv[NSTATE];
    load16(Bv, xp);
    float sd = 0.f;
    for (int t = 0; t < TCHUNK; ++t) {
        int tn = (t + 1 < TCHUNK) ? t + 1 : t;
        float del_n = dp[(size_t)tn * DINNER];
        float uu_n = up[(size_t)tn * DINNER];
        float Bn[NSTATE];
        load16(Bn, xp + (size_t)tn * 128);

        sd += del;
        float du = del * uu;
#pragma unroll
        for (int n = 0; n < NSTATE; ++n)
            h[n] = __expf(del * A[n]) * h[n] + du * Bv[n];

        del = del_n; uu = uu_n;
#pragma unroll
        for (int n = 0; n < NSTATE; ++n) Bv[n] = Bn[n];
    }
    size_t idx = ((size_t)(b * NCHUNK + c) * DINNER + d);
#pragma unroll
    for (int q = 0; q < 4; ++q)
        *(float4*)(hloc + idx * NSTATE + q * 4) = *(float4*)(h + q * 4);
    sumdelta[idx] = sd;
}

// combine: one thread per (b,d,n); serial over chunks; IN PLACE: hloc[c] := state BEFORE chunk c
__global__ __launch_bounds__(256) void scan_combine(float* __restrict__ hloc,
                                                    const float* __restrict__ sumdelta,
                                                    const float* __restrict__ A_log) {
    int g = blockIdx.x * 256 + threadIdx.x;       // 0 .. B*D*N-1
    int n = g & 15;
    int d = (g >> 4) & (DINNER - 1);
    int b = g >> 14;
    float A = -__expf(A_log[d * NSTATE + n]);
    float h = 0.f;
    for (int c = 0; c < NCHUNK; ++c) {
        size_t idx = ((size_t)(b * NCHUNK + c) * DINNER + d) * NSTATE + n;
        float loc = hloc[idx];
        hloc[idx] = h;
        h = __expf(A * sumdelta[((size_t)(b * NCHUNK + c) * DINNER + d)]) * h + loc;
    }
}

// pass 2: rerun scan with true h0 (in hloc), compute y, fuse *silu(z), write f16
__global__ __launch_bounds__(256) void scan_pass2(const float* __restrict__ delta,
                                                  const float* __restrict__ u,
                                                  const float* __restrict__ xdbl,
                                                  const float* __restrict__ A_log,
                                                  const float* __restrict__ Dv,
                                                  const float* __restrict__ h0,
                                                  const f16* __restrict__ xz,
                                                  f16* __restrict__ y16) {
    int blk = blockIdx.x;
    int dg = blk & 3;
    int c = (blk >> 2) & (NCHUNK - 1);
    int b = blk >> 8;
    int d = dg * 256 + threadIdx.x;

    float A[NSTATE];
#pragma unroll
    for (int n = 0; n < NSTATE; ++n) A[n] = -__expf(A_log[d * NSTATE + n]);
    float Dval = Dv[d];
    float h[NSTATE];
    size_t idx = ((size_t)(b * NCHUNK + c) * DINNER + d);
#pragma unroll
    for (int q = 0; q < 4; ++q)
        *(float4*)(h + q * 4) = *(const float4*)(h0 + idx * NSTATE + q * 4);

    size_t rbase = (size_t)b * LSEQ + (size_t)c * TCHUNK;
    const float* dp = delta + rbase * DINNER + d;
    const float* up = u + rbase * DINNER + d;
    const float* xp = xdbl + rbase * 128 + 32;
    const f16* zp = xz + rbase * (2 * DINNER) + DINNER + d;
    f16* yp = y16 + rbase * DINNER + d;

    float del = dp[0], uu = up[0];
    float Bv[NSTATE], Cv[NSTATE];
    load16(Bv, xp);
    load16(Cv, xp + 16);
    for (int t = 0; t < TCHUNK; ++t) {
        int tn = (t + 1 < TCHUNK) ? t + 1 : t;
        float del_n = dp[(size_t)tn * DINNER];
        float uu_n = up[(size_t)tn * DINNER];
        float Bn[NSTATE], Cn[NSTATE];
        load16(Bn, xp + (size_t)tn * 128);
        load16(Cn, xp + (size_t)tn * 128 + 16);
        float z = (float)zp[(size_t)t * (2 * DINNER)];

        float du = del * uu;
        float yv = 0.f;
#pragma unroll
        for (int n = 0; n < NSTATE; ++n) {
            h[n] = __expf(del * A[n]) * h[n] + du * Bv[n];
            yv += h[n] * Cv[n];
        }
        yv += uu * Dval;
        float sz = z / (1.f + __expf(-z));
        yp[(size_t)t * DINNER] = (f16)(yv * sz);

        del = del_n; uu = uu_n;
#pragma unroll
        for (int n = 0; n < NSTATE; ++n) { Bv[n] = Bn[n]; Cv[n] = Cn[n]; }
    }
}

// ---------------------------------------------------------------- output LNs
__global__ __launch_bounds__(256) void ln_match(const float* __restrict__ resid,
                                                const float* __restrict__ raw,
                                                const float* __restrict__ mb,
                                                const float* __restrict__ w,
                                                const float* __restrict__ b,
                                                float* __restrict__ out) {
    int row = blockIdx.x * 4 + (threadIdx.x >> 6);
    int lane = threadIdx.x & 63;
    float vv[8];
#pragma unroll
    for (int j = 0; j < 8; ++j) {
        int c = lane * 8 + j;
        vv[j] = resid[(size_t)row * DMODEL + c] + raw[(size_t)row * DMODEL + c] + mb[c];
    }
    float s = 0.f, sq = 0.f;
#pragma unroll
    for (int j = 0; j < 8; ++j) { s += vv[j]; sq += vv[j] * vv[j]; }
    s = wave_sum(s); sq = wave_sum(sq);
    float mu = s * (1.f / DMODEL);
    float rstd = rsqrtf(sq * (1.f / DMODEL) - mu * mu + LN_EPS);
    float ov[8];
#pragma unroll
    for (int j = 0; j < 8; ++j) {
        int c = lane * 8 + j;
        ov[j] = (vv[j] - mu) * rstd * w[c] + b[c];
    }
    float* op = out + (size_t)row * DMODEL + lane * 8;
    *(float4*)(op) = *(float4*)(ov);
    *(float4*)(op + 4) = *(float4*)(ov + 4);
}

__global__ __launch_bounds__(256) void ln_geom(const float* __restrict__ raw,
                                               const float* __restrict__ gb,
                                               const float* __restrict__ w,
                                               const float* __restrict__ b,
                                               float* __restrict__ out) {
    const int DG = 256;
    int row = blockIdx.x * 4 + (threadIdx.x >> 6);
    int lane = threadIdx.x & 63;
    float vv[4];
#pragma unroll
    for (int j = 0; j < 4; ++j) {
        int c = lane * 4 + j;
        vv[j] = raw[(size_t)row * DG + c] + gb[c];
    }
    float s = 0.f, sq = 0.f;
#pragma unroll
    for (int j = 0; j < 4; ++j) { s += vv[j]; sq += vv[j] * vv[j]; }
    s = wave_sum(s); sq = wave_sum(sq);
    float mu = s * (1.f / DG);
    float rstd = rsqrtf(sq * (1.f / DG) - mu * mu + LN_EPS);
    float ov[4];
#pragma unroll
    for (int j = 0; j < 4; ++j) {
        int c = lane * 4 + j;
        ov[j] = (vv[j] - mu) * rstd * w[c] + b[c];
    }
    *(float4*)(out + (size_t)row * DG + lane * 4) = *(float4*)(ov);
}

// ---------------------------------------------------------------- launcher
extern "C" void kernel_launch(void* const* d_in, const int* in_sizes, int n_in,
                              void* d_out, int out_size, void* d_ws, size_t ws_size,
                              hipStream_t stream) {
    const float* x         = (const float*)d_in[0];
    const float* norm_w    = (const float*)d_in[1];
    const float* norm_b    = (const float*)d_in[2];
    const float* in_proj_w = (const float*)d_in[3];
    const float* conv_w    = (const float*)d_in[4];
    const float* conv_b    = (const float*)d_in[5];
    const float* x_proj_w  = (const float*)d_in[6];
    const float* dt_proj_w = (const float*)d_in[7];
    const float* dt_proj_b = (const float*)d_in[8];
    const float* A_log     = (const float*)d_in[9];
    const float* Dvec      = (const float*)d_in[10];
    const float* mix_out_w = (const float*)d_in[11];
    const float* match_w   = (const float*)d_in[12];
    const float* match_b   = (const float*)d_in[13];
    const float* geom_w    = (const float*)d_in[14];
    const float* geom_b    = (const float*)d_in[15];
    const float* normm_w   = (const float*)d_in[16];
    const float* normm_b   = (const float*)d_in[17];
    const float* normg_w   = (const float*)d_in[18];
    const float* normg_b   = (const float*)d_in[19];

    char* ws = (char*)d_ws;
    // workspace layout (bytes) — 134.8 MB total
    f16* h16    = (f16*)(ws + 0);            // 8 MB  (reused: sumdelta during scan, hm16 after)
    f16* wip    = (f16*)(ws + 8388608);      // weights, contiguous from here (cvt_weights)
    f16* wxp    = (f16*)(ws + 10485760);
    f16* wdt    = (f16*)(ws + 10747904);
    f16* wmo    = (f16*)(ws + 10813440);
    f16* wma    = (f16*)(ws + 11862016);
    f16* wge    = (f16*)(ws + 12386304);
    f16* xz16   = (f16*)(ws + 12648448);     // 32 MB
    f16* xmc16  = (f16*)(ws + 46202880);     // 16 MB (xm f16; reused as y16 after x_proj)
    float* xmcf = (float*)(ws + 62980096);   // 32 MB (u; reused: traw+graw after pass2)
    float* xdbl = (float*)(ws + 96534528);   // 4 MB
    f16* dt16   = (f16*)(ws + 100728832);    // 512 KB
    float* delta = (float*)(ws + 101253120); // 32 MB

    // scan scratch: hloc (16 MB) lives in d_out (24 MB, only written by final LNs)
    float* hloc     = (float*)d_out;
    float* sumdelta = (float*)h16;           // 1 MB over dead h16 region

    f16* hm16 = h16;
    f16* y16 = xmc16;
    float* traw = xmcf;
    float* graw = xmcf + (size_t)NROWS * DMODEL;
    float* out0 = (float*)d_out;
    float* out1 = out0 + (size_t)NROWS * DMODEL;

    // 1. LayerNorm(x) -> h16
    ln_x_to_f16<<<NROWS / 4, 256, 0, stream>>>(x, norm_w, norm_b, h16);
    // 2. all weight conversions (single kernel; outputs contiguous at wip)
    cvt_weights<<<2080, 256, 0, stream>>>(in_proj_w, x_proj_w, dt_proj_w,
                                          mix_out_w, match_w, geom_w, wip);
    // 3. xz = h @ in_proj^T
    gemm_xwt<1><<<dim3(16, 64), 256, 0, stream>>>(h16, wip, xz16, 512, 2048, nullptr, nullptr);
    // 4. conv + silu
    conv_silu<<<2048, 256, 0, stream>>>(xz16, conv_w, conv_b, xmc16, xmcf);
    // 5. x_dbl = xm @ x_proj^T (f32 ld128) + dt16 fused
    gemm_xwt<3><<<dim3(1, 64), 256, 0, stream>>>(xmc16, wxp, xdbl, 1024, 128, nullptr, dt16);
    // 6. delta = softplus(dt @ dt_proj^T + b)  (fused epilogue)
    gemm_xwt<2><<<dim3(8, 64), 256, 0, stream>>>(dt16, wdt, delta, 32, 1024, dt_proj_b, nullptr);
    // 7. chunked selective scan
    scan_pass1<<<NB * NCHUNK * 4, 256, 0, stream>>>(delta, xmcf, xdbl, A_log, hloc, sumdelta);
    scan_combine<<<NB * DINNER * NSTATE / 256, 256, 0, stream>>>(hloc, sumdelta, A_log);
    scan_pass2<<<NB * NCHUNK * 4, 256, 0, stream>>>(delta, xmcf, xdbl, A_log, Dvec, hloc, xz16, y16);
    // 8. hm = y @ mix_out^T
    gemm_xwt<1><<<dim3(4, 64), 256, 0, stream>>>(y16, wmo, hm16, 1024, 512, nullptr, nullptr);
    // 9. match / geom GEMMs
    gemm_xwt<0><<<dim3(4, 64), 256, 0, stream>>>(hm16, wma, traw, 512, 512, nullptr, nullptr);
    gemm_xwt<0><<<dim3(2, 64), 256, 0, stream>>>(hm16, wge, graw, 512, 256, nullptr, nullptr);
    // 10. output layernorms (write d_out; hloc dead by now)
    ln_match<<<NROWS / 4, 256, 0, stream>>>(x, traw, match_b, normm_w, normm_b, out0);
    ln_geom<<<NROWS / 4, 256, 0, stream>>>(graw, geom_b, normg_w, normg_b, out1);
}

// Round 4
// 361.891 us; speedup vs baseline: 4.1443x; 1.0523x over previous
//
#include <hip/hip_runtime.h>
#include <hip/hip_bf16.h>

#define NB 4
#define LSEQ 2048
#define NROWS (NB * LSEQ)        // 8192
#define DMODEL 512
#define DINNER 1024
#define NSTATE 16
#define DTRANK 32
#define LN_EPS 1e-5f

#define NCHUNK 64
#define TCHUNK 32               // NCHUNK * TCHUNK == LSEQ

typedef _Float16 f16;
typedef _Float16 f16x8 __attribute__((ext_vector_type(8)));
typedef float f32x4 __attribute__((ext_vector_type(4)));

// ---------------------------------------------------------------- utilities
__device__ inline float wave_sum(float v) {
#pragma unroll
    for (int off = 32; off; off >>= 1) v += __shfl_xor(v, off, 64);
    return v;
}

__device__ inline void load16(float* dst, const float* src) {
    float4* d4 = (float4*)dst; const float4* s4 = (const float4*)src;
    d4[0] = s4[0]; d4[1] = s4[1]; d4[2] = s4[2]; d4[3] = s4[3];
}

// ---------------------------------------------------------------- LN(x) -> f16
__global__ __launch_bounds__(256) void ln_x_to_f16(const float* __restrict__ x,
                                                   const float* __restrict__ w,
                                                   const float* __restrict__ b,
                                                   f16* __restrict__ out) {
    int row = blockIdx.x * 4 + (threadIdx.x >> 6);
    int lane = threadIdx.x & 63;
    const float* xr = x + (size_t)row * DMODEL + lane * 8;
    float vv[8];
    *(float4*)(vv) = *(const float4*)(xr);
    *(float4*)(vv + 4) = *(const float4*)(xr + 4);
    float s = 0.f, sq = 0.f;
#pragma unroll
    for (int j = 0; j < 8; ++j) { s += vv[j]; sq += vv[j] * vv[j]; }
    s = wave_sum(s); sq = wave_sum(sq);
    float mu = s * (1.f / DMODEL);
    float rstd = rsqrtf(sq * (1.f / DMODEL) - mu * mu + LN_EPS);
    f16x8 o;
#pragma unroll
    for (int j = 0; j < 8; ++j) {
        int c = lane * 8 + j;
        o[j] = (f16)((vv[j] - mu) * rstd * w[c] + b[c]);
    }
    *(f16x8*)(out + (size_t)row * DMODEL + lane * 8) = o;
}

// ---------------------------------------------------------------- all weight conversions, one kernel
__global__ void cvt_weights(const float* __restrict__ ip, const float* __restrict__ xp,
                            const float* __restrict__ dt, const float* __restrict__ mo,
                            const float* __restrict__ ma, const float* __restrict__ ge,
                            f16* __restrict__ out) {
    int i = blockIdx.x * 256 + threadIdx.x;
    int stride = gridDim.x * 256;
    for (; i < 2129920; i += stride) {
        float v;
        if (i < 1048576) v = ip[i];
        else if (i < 1179648) { int j = i - 1048576; v = (j < 65536) ? xp[j] : 0.f; }
        else if (i < 1212416) v = dt[i - 1179648];
        else if (i < 1736704) v = mo[i - 1212416];
        else if (i < 1998848) v = ma[i - 1736704];
        else v = ge[i - 1998848];
        out[i] = (f16)v;
    }
}

// ---------------------------------------------------------------- GEMM: C[M,N] = X[M,K] @ W[N,K]^T
// 128x128 tile, BK=32, 4 waves; global_load_lds staging, 2-phase double buffer.
// MODE 0: f32 out | 1: f16 out | 2: f32 softplus(v+bias[col]) | 3: f32 out(ld128) + f16 aux col<32
template <int MODE>
__global__ __launch_bounds__(256) void gemm_xwt(const f16* __restrict__ X,
                                                const f16* __restrict__ W,
                                                void* __restrict__ Out,
                                                int K, int ldc,
                                                const float* __restrict__ bias,
                                                f16* __restrict__ aux) {
    __shared__ __align__(16) f16 As[2][128 * 32];
    __shared__ __align__(16) f16 Bs[2][128 * 32];
    const int tid = threadIdx.x;
    const int lane = tid & 63;
    const int wv = tid >> 6;
    const int wr = wv >> 1, wc = wv & 1;
    const int rowbase = blockIdx.y * 128;
    const int colbase = blockIdx.x * 128;

    const f32x4 zero = {0.f, 0.f, 0.f, 0.f};
    f32x4 acc[4][4];
#pragma unroll
    for (int m = 0; m < 4; ++m)
#pragma unroll
        for (int n = 0; n < 4; ++n) acc[m][n] = zero;

    const int nk = K >> 5;
    auto stage = [&](int buf, int kt) {
        const int k0 = kt << 5;
#pragma unroll
        for (int it = 0; it < 2; ++it) {
            int id = it * 256 + wv * 64 + lane;     // 0..511
            int row = id >> 2;
            int k8 = (id & 3) << 3;
            const f16* ga = X + (size_t)(rowbase + row) * K + k0 + k8;
            const f16* gb = W + (size_t)(colbase + row) * K + k0 + k8;
            __builtin_amdgcn_global_load_lds(
                (const __attribute__((address_space(1))) void*)ga,
                (__attribute__((address_space(3))) void*)(&As[buf][(it * 256 + wv * 64) * 8]), 16, 0, 0);
            __builtin_amdgcn_global_load_lds(
                (const __attribute__((address_space(1))) void*)gb,
                (__attribute__((address_space(3))) void*)(&Bs[buf][(it * 256 + wv * 64) * 8]), 16, 0, 0);
        }
    };

    stage(0, 0);
    __syncthreads();
    for (int kt = 0; kt < nk; ++kt) {
        const int cur = kt & 1;
        if (kt + 1 < nk) stage(cur ^ 1, kt + 1);    // prefetch overlaps MFMA below
        f16x8 af[4], bf[4];
#pragma unroll
        for (int m = 0; m < 4; ++m)
            af[m] = *(const f16x8*)(&As[cur][(wr * 64 + m * 16 + (lane & 15)) * 32 + ((lane >> 4) << 3)]);
#pragma unroll
        for (int n = 0; n < 4; ++n)
            bf[n] = *(const f16x8*)(&Bs[cur][(wc * 64 + n * 16 + (lane & 15)) * 32 + ((lane >> 4) << 3)]);
#pragma unroll
        for (int m = 0; m < 4; ++m)
#pragma unroll
            for (int n = 0; n < 4; ++n)
                acc[m][n] = __builtin_amdgcn_mfma_f32_16x16x32_f16(af[m], bf[n], acc[m][n], 0, 0, 0);
        __syncthreads();   // barrier drain covers both the prefetch vmem and peers' ds_reads
    }
#pragma unroll
    for (int m = 0; m < 4; ++m) {
        int r0 = rowbase + wr * 64 + m * 16 + ((lane >> 4) << 2);
#pragma unroll
        for (int n = 0; n < 4; ++n) {
            int c = colbase + wc * 64 + n * 16 + (lane & 15);
#pragma unroll
            for (int r = 0; r < 4; ++r) {
                float v = acc[m][n][r];
                size_t o = (size_t)(r0 + r) * ldc + c;
                if (MODE == 1) {
                    ((f16*)Out)[o] = (f16)v;
                } else if (MODE == 2) {
                    float t = v + bias[c];
                    ((float*)Out)[o] = fmaxf(t, 0.f) + log1pf(__expf(-fabsf(t)));
                } else if (MODE == 3) {
                    ((float*)Out)[o] = v;
                    if (c < DTRANK) aux[(size_t)(r0 + r) * DTRANK + c] = (f16)v;
                } else {
                    ((float*)Out)[o] = v;
                }
            }
        }
    }
}

// ---------------------------------------------------------------- causal depthwise conv + silu (x8 vectorized)
__global__ __launch_bounds__(256) void conv_silu(const f16* __restrict__ xz,
                                                 const float* __restrict__ cw,
                                                 const float* __restrict__ cb,
                                                 f16* __restrict__ out16) {
    int i = blockIdx.x * 256 + threadIdx.x;          // one per 8 channels
    int dg = i & 127;                                // DINNER/8 groups
    int row = i >> 7;
    int t = row & (LSEQ - 1);
    int d0 = dg * 8;
    float acc[8];
    float4 cwv[8];
#pragma unroll
    for (int k = 0; k < 8; ++k) {
        acc[k] = cb[d0 + k];
        cwv[k] = *(const float4*)(cw + (d0 + k) * 4);
    }
#pragma unroll
    for (int j = 0; j < 4; ++j) {
        int tt = t - 3 + j;
        if (tt >= 0) {
            f16x8 v = *(const f16x8*)(xz + (size_t)(row - 3 + j) * (2 * DINNER) + d0);
#pragma unroll
            for (int k = 0; k < 8; ++k) acc[k] += cwv[k][j] * (float)v[k];
        }
    }
    f16x8 o;
#pragma unroll
    for (int k = 0; k < 8; ++k) {
        float s = acc[k] / (1.f + __expf(-acc[k]));
        o[k] = (f16)s;
    }
    *(f16x8*)(out16 + (size_t)row * DINNER + d0) = o;
}

// ---------------------------------------------------------------- chunked scan
// pass 1: per (b, chunk, d) local scan from h=0; store end state + sum(delta)
__global__ __launch_bounds__(256) void scan_pass1(const float* __restrict__ delta,
                                                  const f16* __restrict__ u,
                                                  const float* __restrict__ xdbl,
                                                  const float* __restrict__ A_log,
                                                  float* __restrict__ hloc,
                                                  float* __restrict__ sumdelta) {
    int blk = blockIdx.x;
    int dg = blk & 3;
    int c = (blk >> 2) & (NCHUNK - 1);
    int b = blk >> 8;
    int d = dg * 256 + threadIdx.x;

    float A[NSTATE];
    bool fast = true;
#pragma unroll
    for (int n = 0; n < NSTATE; ++n) {
        float a = __expf(A_log[d * NSTATE + n]);
        A[n] = -a;
        fast = fast && (a == (float)(n + 1));
    }
    float h[NSTATE];
#pragma unroll
    for (int n = 0; n < NSTATE; ++n) h[n] = 0.f;

    size_t rbase = (size_t)b * LSEQ + (size_t)c * TCHUNK;
    const float* dp = delta + rbase * DINNER + d;
    const f16* up = u + rbase * DINNER + d;
    const float* xp = xdbl + rbase * 128 + 32;

    float del = dp[0], uu = (float)up[0];
    float Bv[NSTATE];
    load16(Bv, xp);
    float sd = 0.f;
    for (int t = 0; t < TCHUNK; ++t) {
        int tn = (t + 1 < TCHUNK) ? t + 1 : t;
        float del_n = dp[(size_t)tn * DINNER];
        float uu_n = (float)up[(size_t)tn * DINNER];
        float Bn[NSTATE];
        load16(Bn, xp + (size_t)tn * 128);

        sd += del;
        float du = del * uu;
        if (fast) {
            float e1 = __expf(-del);
            float p = e1;
#pragma unroll
            for (int n = 0; n < NSTATE; ++n) {
                h[n] = p * h[n] + du * Bv[n];
                p *= e1;
            }
        } else {
#pragma unroll
            for (int n = 0; n < NSTATE; ++n)
                h[n] = __expf(del * A[n]) * h[n] + du * Bv[n];
        }
        del = del_n; uu = uu_n;
#pragma unroll
        for (int n = 0; n < NSTATE; ++n) Bv[n] = Bn[n];
    }
    size_t idx = ((size_t)(b * NCHUNK + c) * DINNER + d);
#pragma unroll
    for (int q = 0; q < 4; ++q)
        *(float4*)(hloc + idx * NSTATE + q * 4) = *(float4*)(h + q * 4);
    sumdelta[idx] = sd;
}

// combine: one thread per (b,d,n); serial over chunks; IN PLACE: hloc[c] := state BEFORE chunk c
__global__ __launch_bounds__(256) void scan_combine(float* __restrict__ hloc,
                                                    const float* __restrict__ sumdelta,
                                                    const float* __restrict__ A_log) {
    int g = blockIdx.x * 256 + threadIdx.x;
    int n = g & 15;
    int d = (g >> 4) & (DINNER - 1);
    int b = g >> 14;
    float A = -__expf(A_log[d * NSTATE + n]);
    float h = 0.f;
    for (int c = 0; c < NCHUNK; ++c) {
        size_t idx = ((size_t)(b * NCHUNK + c) * DINNER + d) * NSTATE + n;
        float loc = hloc[idx];
        hloc[idx] = h;
        h = __expf(A * sumdelta[((size_t)(b * NCHUNK + c) * DINNER + d)]) * h + loc;
    }
}

// pass 2: rerun scan with true h0 (in hloc), compute y, fuse *silu(z); y16 written IN PLACE over u
__global__ __launch_bounds__(256) void scan_pass2(const float* __restrict__ delta,
                                                  const f16* __restrict__ u,
                                                  const float* __restrict__ xdbl,
                                                  const float* __restrict__ A_log,
                                                  const float* __restrict__ Dv,
                                                  const float* __restrict__ h0,
                                                  const f16* __restrict__ xz,
                                                  f16* __restrict__ y16) {
    int blk = blockIdx.x;
    int dg = blk & 3;
    int c = (blk >> 2) & (NCHUNK - 1);
    int b = blk >> 8;
    int d = dg * 256 + threadIdx.x;

    float A[NSTATE];
    bool fast = true;
#pragma unroll
    for (int n = 0; n < NSTATE; ++n) {
        float a = __expf(A_log[d * NSTATE + n]);
        A[n] = -a;
        fast = fast && (a == (float)(n + 1));
    }
    float Dval = Dv[d];
    float h[NSTATE];
    size_t idx = ((size_t)(b * NCHUNK + c) * DINNER + d);
#pragma unroll
    for (int q = 0; q < 4; ++q)
        *(float4*)(h + q * 4) = *(const float4*)(h0 + idx * NSTATE + q * 4);

    size_t rbase = (size_t)b * LSEQ + (size_t)c * TCHUNK;
    const float* dp = delta + rbase * DINNER + d;
    const f16* up = u + rbase * DINNER + d;
    const float* xp = xdbl + rbase * 128 + 32;
    const f16* zp = xz + rbase * (2 * DINNER) + DINNER + d;
    f16* yp = y16 + rbase * DINNER + d;

    float del = dp[0], uu = (float)up[0];
    float Bv[NSTATE], Cv[NSTATE];
    load16(Bv, xp);
    load16(Cv, xp + 16);
    for (int t = 0; t < TCHUNK; ++t) {
        int tn = (t + 1 < TCHUNK) ? t + 1 : t;
        float del_n = dp[(size_t)tn * DINNER];
        float uu_n = (float)up[(size_t)tn * DINNER];
        float Bn[NSTATE], Cn[NSTATE];
        load16(Bn, xp + (size_t)tn * 128);
        load16(Cn, xp + (size_t)tn * 128 + 16);
        float z = (float)zp[(size_t)t * (2 * DINNER)];

        float du = del * uu;
        float yv = 0.f;
        if (fast) {
            float e1 = __expf(-del);
            float p = e1;
#pragma unroll
            for (int n = 0; n < NSTATE; ++n) {
                h[n] = p * h[n] + du * Bv[n];
                yv += h[n] * Cv[n];
                p *= e1;
            }
        } else {
#pragma unroll
            for (int n = 0; n < NSTATE; ++n) {
                h[n] = __expf(del * A[n]) * h[n] + du * Bv[n];
                yv += h[n] * Cv[n];
            }
        }
        yv += uu * Dval;
        float sz = z / (1.f + __expf(-z));
        yp[(size_t)t * DINNER] = (f16)(yv * sz);   // in-place over u: u[t] already consumed

        del = del_n; uu = uu_n;
#pragma unroll
        for (int n = 0; n < NSTATE; ++n) { Bv[n] = Bn[n]; Cv[n] = Cn[n]; }
    }
}

// ---------------------------------------------------------------- fused output LNs
// blocks [0,2048): match rows; [2048,4096): geom rows. traw has ld 768 (match cols 0..511, geom 512..767)
__global__ __launch_bounds__(256) void ln_outputs(const float* __restrict__ x,
                                                  const float* __restrict__ traw,
                                                  const float* __restrict__ mb,
                                                  const float* __restrict__ gb,
                                                  const float* __restrict__ wm,
                                                  const float* __restrict__ bm,
                                                  const float* __restrict__ wg,
                                                  const float* __restrict__ bg,
                                                  float* __restrict__ out0,
                                                  float* __restrict__ out1) {
    int bid = blockIdx.x;
    int lane = threadIdx.x & 63;
    if (bid < NROWS / 4) {
        int row = bid * 4 + (threadIdx.x >> 6);
        float vv[8];
#pragma unroll
        for (int j = 0; j < 8; ++j) {
            int c = lane * 8 + j;
            vv[j] = x[(size_t)row * DMODEL + c] + traw[(size_t)row * 768 + c] + mb[c];
        }
        float s = 0.f, sq = 0.f;
#pragma unroll
        for (int j = 0; j < 8; ++j) { s += vv[j]; sq += vv[j] * vv[j]; }
        s = wave_sum(s); sq = wave_sum(sq);
        float mu = s * (1.f / DMODEL);
        float rstd = rsqrtf(sq * (1.f / DMODEL) - mu * mu + LN_EPS);
        float ov[8];
#pragma unroll
        for (int j = 0; j < 8; ++j) {
            int c = lane * 8 + j;
            ov[j] = (vv[j] - mu) * rstd * wm[c] + bm[c];
        }
        float* op = out0 + (size_t)row * DMODEL + lane * 8;
        *(float4*)(op) = *(float4*)(ov);
        *(float4*)(op + 4) = *(float4*)(ov + 4);
    } else {
        const int DG = 256;
        int row = (bid - NROWS / 4) * 4 + (threadIdx.x >> 6);
        float vv[4];
#pragma unroll
        for (int j = 0; j < 4; ++j) {
            int c = lane * 4 + j;
            vv[j] = traw[(size_t)row * 768 + 512 + c] + gb[c];
        }
        float s = 0.f, sq = 0.f;
#pragma unroll
        for (int j = 0; j < 4; ++j) { s += vv[j]; sq += vv[j] * vv[j]; }
        s = wave_sum(s); sq = wave_sum(sq);
        float mu = s * (1.f / DG);
        float rstd = rsqrtf(sq * (1.f / DG) - mu * mu + LN_EPS);
        float ov[4];
#pragma unroll
        for (int j = 0; j < 4; ++j) {
            int c = lane * 4 + j;
            ov[j] = (vv[j] - mu) * rstd * wg[c] + bg[c];
        }
        *(float4*)(out1 + (size_t)row * DG + lane * 4) = *(float4*)(ov);
    }
}

// ---------------------------------------------------------------- launcher
extern "C" void kernel_launch(void* const* d_in, const int* in_sizes, int n_in,
                              void* d_out, int out_size, void* d_ws, size_t ws_size,
                              hipStream_t stream) {
    const float* x         = (const float*)d_in[0];
    const float* norm_w    = (const float*)d_in[1];
    const float* norm_b    = (const float*)d_in[2];
    const float* in_proj_w = (const float*)d_in[3];
    const float* conv_w    = (const float*)d_in[4];
    const float* conv_b    = (const float*)d_in[5];
    const float* x_proj_w  = (const float*)d_in[6];
    const float* dt_proj_w = (const float*)d_in[7];
    const float* dt_proj_b = (const float*)d_in[8];
    const float* A_log     = (const float*)d_in[9];
    const float* Dvec      = (const float*)d_in[10];
    const float* mix_out_w = (const float*)d_in[11];
    const float* match_w   = (const float*)d_in[12];
    const float* match_b   = (const float*)d_in[13];
    const float* geom_w    = (const float*)d_in[14];
    const float* geom_b    = (const float*)d_in[15];
    const float* normm_w   = (const float*)d_in[16];
    const float* normm_b   = (const float*)d_in[17];
    const float* normg_w   = (const float*)d_in[18];
    const float* normg_b   = (const float*)d_in[19];

    char* ws = (char*)d_ws;
    // workspace layout (bytes)
    f16* h16    = (f16*)(ws + 0);            // 8 MB  (reused: sumdelta during scan, hm16 after)
    f16* wip    = (f16*)(ws + 8388608);      // weights contiguous from here (cvt_weights)
    f16* wxp    = (f16*)(ws + 10485760);
    f16* wdt    = (f16*)(ws + 10747904);
    f16* wmo    = (f16*)(ws + 10813440);
    f16* wma    = (f16*)(ws + 11862016);     // match+geom contiguous: (768, 512)
    f16* xz16   = (f16*)(ws + 12648448);     // 32 MB
    f16* xmc16  = (f16*)(ws + 46202880);     // 16 MB: u (f16); pass2 writes y16 IN PLACE here
    float* xmcf = (float*)(ws + 62980096);   // 32 MB: traw (8192x768 f32 = 25.2 MB)
    float* xdbl = (float*)(ws + 96534528);   // 4 MB
    f16* dt16   = (f16*)(ws + 100728832);    // 512 KB
    float* delta = (float*)(ws + 101253120); // 32 MB

    // scan scratch: hloc (16.8 MB) lives in d_out (25.2 MB, only written by final LNs)
    float* hloc     = (float*)d_out;
    float* sumdelta = (float*)h16;           // 1 MB over dead h16 region

    f16* hm16 = h16;
    f16* y16 = xmc16;                        // in-place over u
    float* traw = xmcf;                      // ld 768
    float* out0 = (float*)d_out;
    float* out1 = out0 + (size_t)NROWS * DMODEL;

    // 1. LayerNorm(x) -> h16
    ln_x_to_f16<<<NROWS / 4, 256, 0, stream>>>(x, norm_w, norm_b, h16);
    // 2. weight conversions
    cvt_weights<<<2080, 256, 0, stream>>>(in_proj_w, x_proj_w, dt_proj_w,
                                          mix_out_w, match_w, geom_w, wip);
    // 3. xz = h @ in_proj^T
    gemm_xwt<1><<<dim3(16, 64), 256, 0, stream>>>(h16, wip, xz16, 512, 2048, nullptr, nullptr);
    // 4. conv + silu -> u (f16)
    conv_silu<<<NROWS * DINNER / 8 / 256, 256, 0, stream>>>(xz16, conv_w, conv_b, xmc16);
    // 5. x_dbl = xm @ x_proj^T (f32 ld128) + dt16 fused
    gemm_xwt<3><<<dim3(1, 64), 256, 0, stream>>>(xmc16, wxp, xdbl, 1024, 128, nullptr, dt16);
    // 6. delta = softplus(dt @ dt_proj^T + b)
    gemm_xwt<2><<<dim3(8, 64), 256, 0, stream>>>(dt16, wdt, delta, 32, 1024, dt_proj_b, nullptr);
    // 7. chunked selective scan
    scan_pass1<<<NB * NCHUNK * 4, 256, 0, stream>>>(delta, xmc16, xdbl, A_log, hloc, sumdelta);
    scan_combine<<<NB * DINNER * NSTATE / 256, 256, 0, stream>>>(hloc, sumdelta, A_log);
    scan_pass2<<<NB * NCHUNK * 4, 256, 0, stream>>>(delta, xmc16, xdbl, A_log, Dvec, hloc, xz16, y16);
    // 8. hm = y @ mix_out^T
    gemm_xwt<1><<<dim3(4, 64), 256, 0, stream>>>(y16, wmo, hm16, 1024, 512, nullptr, nullptr);
    // 9. match+geom fused GEMM (N=768, contiguous weights)
    gemm_xwt<0><<<dim3(6, 64), 256, 0, stream>>>(hm16, wma, traw, 512, 768, nullptr, nullptr);
    // 10. fused output layernorms (d_out; hloc dead by now)
    ln_outputs<<<NROWS / 2, 256, 0, stream>>>(x, traw, match_b, geom_b,
                                              normm_w, normm_b, normg_w, normg_b, out0, out1);
}

// Round 5
// 348.283 us; speedup vs baseline: 4.3062x; 1.0391x over previous
//
#include <hip/hip_runtime.h>
#include <hip/hip_bf16.h>

#define NB 4
#define LSEQ 2048
#define NROWS (NB * LSEQ)        // 8192
#define DMODEL 512
#define DINNER 1024
#define NSTATE 16
#define DTRANK 32
#define LN_EPS 1e-5f

#define NCHUNK 64
#define TCHUNK 32               // NCHUNK * TCHUNK == LSEQ

typedef _Float16 f16;
typedef _Float16 f16x8 __attribute__((ext_vector_type(8)));
typedef float f32x4 __attribute__((ext_vector_type(4)));

// ---------------------------------------------------------------- utilities
__device__ inline float wave_sum(float v) {
#pragma unroll
    for (int off = 32; off; off >>= 1) v += __shfl_xor(v, off, 64);
    return v;
}

__device__ inline void load16(float* dst, const float* src) {
    float4* d4 = (float4*)dst; const float4* s4 = (const float4*)src;
    d4[0] = s4[0]; d4[1] = s4[1]; d4[2] = s4[2]; d4[3] = s4[3];
}

// ---------------------------------------------------------------- prep: LN(x)->f16  +  all weight cvt
// blocks [0, 2048): layernorm rows (4/block). blocks [2048, ...): weight conversion grid-stride.
__global__ __launch_bounds__(256) void prep(const float* __restrict__ x,
                                            const float* __restrict__ w,
                                            const float* __restrict__ b,
                                            f16* __restrict__ out,
                                            const float* __restrict__ ip, const float* __restrict__ xp,
                                            const float* __restrict__ dt, const float* __restrict__ mo,
                                            const float* __restrict__ ma, const float* __restrict__ ge,
                                            f16* __restrict__ wout) {
    if (blockIdx.x < NROWS / 4) {
        int row = blockIdx.x * 4 + (threadIdx.x >> 6);
        int lane = threadIdx.x & 63;
        const float* xr = x + (size_t)row * DMODEL + lane * 8;
        float vv[8];
        *(float4*)(vv) = *(const float4*)(xr);
        *(float4*)(vv + 4) = *(const float4*)(xr + 4);
        float s = 0.f, sq = 0.f;
#pragma unroll
        for (int j = 0; j < 8; ++j) { s += vv[j]; sq += vv[j] * vv[j]; }
        s = wave_sum(s); sq = wave_sum(sq);
        float mu = s * (1.f / DMODEL);
        float rstd = rsqrtf(sq * (1.f / DMODEL) - mu * mu + LN_EPS);
        f16x8 o;
#pragma unroll
        for (int j = 0; j < 8; ++j) {
            int c = lane * 8 + j;
            o[j] = (f16)((vv[j] - mu) * rstd * w[c] + b[c]);
        }
        *(f16x8*)(out + (size_t)row * DMODEL + lane * 8) = o;
    } else {
        int i = (blockIdx.x - NROWS / 4) * 256 + threadIdx.x;
        int stride = (gridDim.x - NROWS / 4) * 256;
        for (; i < 2129920; i += stride) {
            float v;
            if (i < 1048576) v = ip[i];
            else if (i < 1179648) { int j = i - 1048576; v = (j < 65536) ? xp[j] : 0.f; }
            else if (i < 1212416) v = dt[i - 1179648];
            else if (i < 1736704) v = mo[i - 1212416];
            else if (i < 1998848) v = ma[i - 1736704];
            else v = ge[i - 1998848];
            wout[i] = (f16)v;
        }
    }
}

// ---------------------------------------------------------------- GEMM: C[M,N] = X[M,K] @ W[N,K]^T
// 128x128 tile, BK=32, 4 waves; global_load_lds staging, 2-phase double buffer.
// MODE 0: f32 out | 1: f16 out | 2: f16 softplus(v+bias[col]) | 3: f32 out(ld128) + f16 aux col<32
template <int MODE>
__global__ __launch_bounds__(256) void gemm_xwt(const f16* __restrict__ X,
                                                const f16* __restrict__ W,
                                                void* __restrict__ Out,
                                                int K, int ldc,
                                                const float* __restrict__ bias,
                                                f16* __restrict__ aux) {
    __shared__ __align__(16) f16 As[2][128 * 32];
    __shared__ __align__(16) f16 Bs[2][128 * 32];
    const int tid = threadIdx.x;
    const int lane = tid & 63;
    const int wv = tid >> 6;
    const int wr = wv >> 1, wc = wv & 1;
    const int rowbase = blockIdx.y * 128;
    const int colbase = blockIdx.x * 128;

    const f32x4 zero = {0.f, 0.f, 0.f, 0.f};
    f32x4 acc[4][4];
#pragma unroll
    for (int m = 0; m < 4; ++m)
#pragma unroll
        for (int n = 0; n < 4; ++n) acc[m][n] = zero;

    const int nk = K >> 5;
    auto stage = [&](int buf, int kt) {
        const int k0 = kt << 5;
#pragma unroll
        for (int it = 0; it < 2; ++it) {
            int id = it * 256 + wv * 64 + lane;     // 0..511
            int row = id >> 2;
            int k8 = (id & 3) << 3;
            const f16* ga = X + (size_t)(rowbase + row) * K + k0 + k8;
            const f16* gb = W + (size_t)(colbase + row) * K + k0 + k8;
            __builtin_amdgcn_global_load_lds(
                (const __attribute__((address_space(1))) void*)ga,
                (__attribute__((address_space(3))) void*)(&As[buf][(it * 256 + wv * 64) * 8]), 16, 0, 0);
            __builtin_amdgcn_global_load_lds(
                (const __attribute__((address_space(1))) void*)gb,
                (__attribute__((address_space(3))) void*)(&Bs[buf][(it * 256 + wv * 64) * 8]), 16, 0, 0);
        }
    };

    stage(0, 0);
    __syncthreads();
    for (int kt = 0; kt < nk; ++kt) {
        const int cur = kt & 1;
        if (kt + 1 < nk) stage(cur ^ 1, kt + 1);    // prefetch overlaps MFMA below
        f16x8 af[4], bf[4];
#pragma unroll
        for (int m = 0; m < 4; ++m)
            af[m] = *(const f16x8*)(&As[cur][(wr * 64 + m * 16 + (lane & 15)) * 32 + ((lane >> 4) << 3)]);
#pragma unroll
        for (int n = 0; n < 4; ++n)
            bf[n] = *(const f16x8*)(&Bs[cur][(wc * 64 + n * 16 + (lane & 15)) * 32 + ((lane >> 4) << 3)]);
#pragma unroll
        for (int m = 0; m < 4; ++m)
#pragma unroll
            for (int n = 0; n < 4; ++n)
                acc[m][n] = __builtin_amdgcn_mfma_f32_16x16x32_f16(af[m], bf[n], acc[m][n], 0, 0, 0);
        __syncthreads();
    }
#pragma unroll
    for (int m = 0; m < 4; ++m) {
        int r0 = rowbase + wr * 64 + m * 16 + ((lane >> 4) << 2);
#pragma unroll
        for (int n = 0; n < 4; ++n) {
            int c = colbase + wc * 64 + n * 16 + (lane & 15);
#pragma unroll
            for (int r = 0; r < 4; ++r) {
                float v = acc[m][n][r];
                size_t o = (size_t)(r0 + r) * ldc + c;
                if (MODE == 1) {
                    ((f16*)Out)[o] = (f16)v;
                } else if (MODE == 2) {
                    float t = v + bias[c];
                    ((f16*)Out)[o] = (f16)(fmaxf(t, 0.f) + log1pf(__expf(-fabsf(t))));
                } else if (MODE == 3) {
                    ((float*)Out)[o] = v;
                    if (c < DTRANK) aux[(size_t)(r0 + r) * DTRANK + c] = (f16)v;
                } else {
                    ((float*)Out)[o] = v;
                }
            }
        }
    }
}

// ---------------------------------------------------------------- causal depthwise conv + silu (x8 vectorized)
__global__ __launch_bounds__(256) void conv_silu(const f16* __restrict__ xz,
                                                 const float* __restrict__ cw,
                                                 const float* __restrict__ cb,
                                                 f16* __restrict__ out16) {
    int i = blockIdx.x * 256 + threadIdx.x;          // one per 8 channels
    int dg = i & 127;                                // DINNER/8 groups
    int row = i >> 7;
    int t = row & (LSEQ - 1);
    int d0 = dg * 8;
    float acc[8];
    float4 cwv[8];
#pragma unroll
    for (int k = 0; k < 8; ++k) {
        acc[k] = cb[d0 + k];
        cwv[k] = *(const float4*)(cw + (d0 + k) * 4);
    }
#pragma unroll
    for (int j = 0; j < 4; ++j) {
        int tt = t - 3 + j;
        if (tt >= 0) {
            f16x8 v = *(const f16x8*)(xz + (size_t)(row - 3 + j) * (2 * DINNER) + d0);
#pragma unroll
            for (int k = 0; k < 8; ++k) acc[k] += cwv[k][j] * (float)v[k];
        }
    }
    f16x8 o;
#pragma unroll
    for (int k = 0; k < 8; ++k) {
        float s = acc[k] / (1.f + __expf(-acc[k]));
        o[k] = (f16)s;
    }
    *(f16x8*)(out16 + (size_t)row * DINNER + d0) = o;
}

// ---------------------------------------------------------------- chunked scan
// dA powers with log-depth mul tree (A[n] = -(n+1) fast path)
__device__ inline void pow_tree(float e1, float* pw) {
    float e2 = e1 * e1, e4 = e2 * e2, e8 = e4 * e4;
    pw[0] = e1;       pw[1] = e2;       pw[2] = e1 * e2;  pw[3] = e4;
    pw[4] = e1 * e4;  pw[5] = e2 * e4;  pw[6] = pw[2] * e4; pw[7] = e8;
    pw[8] = e1 * e8;  pw[9] = e2 * e8;  pw[10] = pw[2] * e8; pw[11] = e4 * e8;
    pw[12] = pw[4] * e8; pw[13] = pw[5] * e8; pw[14] = pw[6] * e8; pw[15] = e8 * e8;
}

// pass 1: per (b, chunk, d) local scan from h=0; store end state + sum(delta)
// B panel staged in LDS (wave-uniform loads -> broadcast ds_read)
__global__ __launch_bounds__(256) void scan_pass1(const f16* __restrict__ delta,
                                                  const f16* __restrict__ u,
                                                  const float* __restrict__ xdbl,
                                                  const float* __restrict__ A_log,
                                                  float* __restrict__ hloc,
                                                  float* __restrict__ sumdelta) {
    __shared__ __align__(16) float bc[TCHUNK][32];
    int blk = blockIdx.x;
    int dg = blk & 3;
    int c = (blk >> 2) & (NCHUNK - 1);
    int b = blk >> 8;
    int d = dg * 256 + threadIdx.x;
    size_t rbase = (size_t)b * LSEQ + (size_t)c * TCHUNK;

    // stage B+C panel: 32 rows x 32 floats, one float4 per thread
    {
        int trow = threadIdx.x >> 3;
        int q = (threadIdx.x & 7) << 2;
        *(float4*)&bc[trow][q] = *(const float4*)(xdbl + (rbase + trow) * 128 + 32 + q);
    }

    float A[NSTATE];
    bool fast = true;
#pragma unroll
    for (int n = 0; n < NSTATE; ++n) {
        float a = __expf(A_log[d * NSTATE + n]);
        A[n] = -a;
        fast = fast && (a == (float)(n + 1));
    }
    float h[NSTATE];
#pragma unroll
    for (int n = 0; n < NSTATE; ++n) h[n] = 0.f;

    const f16* dp = delta + rbase * DINNER + d;
    const f16* up = u + rbase * DINNER + d;
    __syncthreads();

    float del = (float)dp[0], uu = (float)up[0];
    float sd = 0.f;
    for (int t = 0; t < TCHUNK; ++t) {
        int tn = (t + 1 < TCHUNK) ? t + 1 : t;
        float del_n = (float)dp[(size_t)tn * DINNER];
        float uu_n = (float)up[(size_t)tn * DINNER];
        float Bv[NSTATE];
        load16(Bv, &bc[t][0]);

        sd += del;
        float du = del * uu;
        if (fast) {
            float pw[NSTATE];
            pow_tree(__expf(-del), pw);
#pragma unroll
            for (int n = 0; n < NSTATE; ++n)
                h[n] = pw[n] * h[n] + du * Bv[n];
        } else {
#pragma unroll
            for (int n = 0; n < NSTATE; ++n)
                h[n] = __expf(del * A[n]) * h[n] + du * Bv[n];
        }
        del = del_n; uu = uu_n;
    }
    size_t idx = ((size_t)(b * NCHUNK + c) * DINNER + d);
#pragma unroll
    for (int q = 0; q < 4; ++q)
        *(float4*)(hloc + idx * NSTATE + q * 4) = *(float4*)(h + q * 4);
    sumdelta[idx] = sd;
}

// combine: one thread per (b,d,n); serial over chunks; IN PLACE: hloc[c] := state BEFORE chunk c
__global__ __launch_bounds__(256) void scan_combine(float* __restrict__ hloc,
                                                    const float* __restrict__ sumdelta,
                                                    const float* __restrict__ A_log) {
    int g = blockIdx.x * 256 + threadIdx.x;
    int n = g & 15;
    int d = (g >> 4) & (DINNER - 1);
    int b = g >> 14;
    float A = -__expf(A_log[d * NSTATE + n]);
    float h = 0.f;
    for (int c = 0; c < NCHUNK; ++c) {
        size_t idx = ((size_t)(b * NCHUNK + c) * DINNER + d) * NSTATE + n;
        float loc = hloc[idx];
        hloc[idx] = h;
        h = __expf(A * sumdelta[((size_t)(b * NCHUNK + c) * DINNER + d)]) * h + loc;
    }
}

// pass 2: rerun scan with true h0 (in hloc), compute y, fuse *silu(z); y16 written IN PLACE over u
__global__ __launch_bounds__(256) void scan_pass2(const f16* __restrict__ delta,
                                                  const f16* __restrict__ u,
                                                  const float* __restrict__ xdbl,
                                                  const float* __restrict__ A_log,
                                                  const float* __restrict__ Dv,
                                                  const float* __restrict__ h0,
                                                  const f16* __restrict__ xz,
                                                  f16* __restrict__ y16) {
    __shared__ __align__(16) float bc[TCHUNK][32];
    int blk = blockIdx.x;
    int dg = blk & 3;
    int c = (blk >> 2) & (NCHUNK - 1);
    int b = blk >> 8;
    int d = dg * 256 + threadIdx.x;
    size_t rbase = (size_t)b * LSEQ + (size_t)c * TCHUNK;

    {
        int trow = threadIdx.x >> 3;
        int q = (threadIdx.x & 7) << 2;
        *(float4*)&bc[trow][q] = *(const float4*)(xdbl + (rbase + trow) * 128 + 32 + q);
    }

    float A[NSTATE];
    bool fast = true;
#pragma unroll
    for (int n = 0; n < NSTATE; ++n) {
        float a = __expf(A_log[d * NSTATE + n]);
        A[n] = -a;
        fast = fast && (a == (float)(n + 1));
    }
    float Dval = Dv[d];
    float h[NSTATE];
    size_t idx = ((size_t)(b * NCHUNK + c) * DINNER + d);
#pragma unroll
    for (int q = 0; q < 4; ++q)
        *(float4*)(h + q * 4) = *(const float4*)(h0 + idx * NSTATE + q * 4);

    const f16* dp = delta + rbase * DINNER + d;
    const f16* up = u + rbase * DINNER + d;
    const f16* zp = xz + rbase * (2 * DINNER) + DINNER + d;
    f16* yp = y16 + rbase * DINNER + d;
    __syncthreads();

    float del = (float)dp[0], uu = (float)up[0];
    float z = (float)zp[0];
    for (int t = 0; t < TCHUNK; ++t) {
        int tn = (t + 1 < TCHUNK) ? t + 1 : t;
        float del_n = (float)dp[(size_t)tn * DINNER];
        float uu_n = (float)up[(size_t)tn * DINNER];
        float z_n = (float)zp[(size_t)tn * (2 * DINNER)];
        float Bv[NSTATE], Cv[NSTATE];
        load16(Bv, &bc[t][0]);
        load16(Cv, &bc[t][16]);

        float du = del * uu;
        float yv = 0.f;
        if (fast) {
            float pw[NSTATE];
            pow_tree(__expf(-del), pw);
#pragma unroll
            for (int n = 0; n < NSTATE; ++n) {
                h[n] = pw[n] * h[n] + du * Bv[n];
                yv += h[n] * Cv[n];
            }
        } else {
#pragma unroll
            for (int n = 0; n < NSTATE; ++n) {
                h[n] = __expf(del * A[n]) * h[n] + du * Bv[n];
                yv += h[n] * Cv[n];
            }
        }
        yv += uu * Dval;
        float sz = z / (1.f + __expf(-z));
        yp[(size_t)t * DINNER] = (f16)(yv * sz);   // in-place over u: u[t] already consumed

        del = del_n; uu = uu_n; z = z_n;
    }
}

// ---------------------------------------------------------------- fused output LNs
__global__ __launch_bounds__(256) void ln_outputs(const float* __restrict__ x,
                                                  const float* __restrict__ traw,
                                                  const float* __restrict__ mb,
                                                  const float* __restrict__ gb,
                                                  const float* __restrict__ wm,
                                                  const float* __restrict__ bm,
                                                  const float* __restrict__ wg,
                                                  const float* __restrict__ bg,
                                                  float* __restrict__ out0,
                                                  float* __restrict__ out1) {
    int bid = blockIdx.x;
    int lane = threadIdx.x & 63;
    if (bid < NROWS / 4) {
        int row = bid * 4 + (threadIdx.x >> 6);
        float vv[8];
#pragma unroll
        for (int j = 0; j < 8; ++j) {
            int c = lane * 8 + j;
            vv[j] = x[(size_t)row * DMODEL + c] + traw[(size_t)row * 768 + c] + mb[c];
        }
        float s = 0.f, sq = 0.f;
#pragma unroll
        for (int j = 0; j < 8; ++j) { s += vv[j]; sq += vv[j] * vv[j]; }
        s = wave_sum(s); sq = wave_sum(sq);
        float mu = s * (1.f / DMODEL);
        float rstd = rsqrtf(sq * (1.f / DMODEL) - mu * mu + LN_EPS);
        float ov[8];
#pragma unroll
        for (int j = 0; j < 8; ++j) {
            int c = lane * 8 + j;
            ov[j] = (vv[j] - mu) * rstd * wm[c] + bm[c];
        }
        float* op = out0 + (size_t)row * DMODEL + lane * 8;
        *(float4*)(op) = *(float4*)(ov);
        *(float4*)(op + 4) = *(float4*)(ov + 4);
    } else {
        const int DG = 256;
        int row = (bid - NROWS / 4) * 4 + (threadIdx.x >> 6);
        float vv[4];
#pragma unroll
        for (int j = 0; j < 4; ++j) {
            int c = lane * 4 + j;
            vv[j] = traw[(size_t)row * 768 + 512 + c] + gb[c];
        }
        float s = 0.f, sq = 0.f;
#pragma unroll
        for (int j = 0; j < 4; ++j) { s += vv[j]; sq += vv[j] * vv[j]; }
        s = wave_sum(s); sq = wave_sum(sq);
        float mu = s * (1.f / DG);
        float rstd = rsqrtf(sq * (1.f / DG) - mu * mu + LN_EPS);
        float ov[4];
#pragma unroll
        for (int j = 0; j < 4; ++j) {
            int c = lane * 4 + j;
            ov[j] = (vv[j] - mu) * rstd * wg[c] + bg[c];
        }
        *(float4*)(out1 + (size_t)row * DG + lane * 4) = *(float4*)(ov);
    }
}

// ---------------------------------------------------------------- launcher
extern "C" void kernel_launch(void* const* d_in, const int* in_sizes, int n_in,
                              void* d_out, int out_size, void* d_ws, size_t ws_size,
                              hipStream_t stream) {
    const float* x         = (const float*)d_in[0];
    const float* norm_w    = (const float*)d_in[1];
    const float* norm_b    = (const float*)d_in[2];
    const float* in_proj_w = (const float*)d_in[3];
    const float* conv_w    = (const float*)d_in[4];
    const float* conv_b    = (const float*)d_in[5];
    const float* x_proj_w  = (const float*)d_in[6];
    const float* dt_proj_w = (const float*)d_in[7];
    const float* dt_proj_b = (const float*)d_in[8];
    const float* A_log     = (const float*)d_in[9];
    const float* Dvec      = (const float*)d_in[10];
    const float* mix_out_w = (const float*)d_in[11];
    const float* match_w   = (const float*)d_in[12];
    const float* match_b   = (const float*)d_in[13];
    const float* geom_w    = (const float*)d_in[14];
    const float* geom_b    = (const float*)d_in[15];
    const float* normm_w   = (const float*)d_in[16];
    const float* normm_b   = (const float*)d_in[17];
    const float* normg_w   = (const float*)d_in[18];
    const float* normg_b   = (const float*)d_in[19];

    char* ws = (char*)d_ws;
    // workspace layout (bytes)
    f16* h16    = (f16*)(ws + 0);            // 8 MB  (reused: sumdelta during scan, hm16 after)
    f16* wip    = (f16*)(ws + 8388608);      // weights contiguous from here
    f16* wxp    = (f16*)(ws + 10485760);
    f16* wdt    = (f16*)(ws + 10747904);
    f16* wmo    = (f16*)(ws + 10813440);
    f16* wma    = (f16*)(ws + 11862016);     // match+geom contiguous: (768, 512)
    f16* xz16   = (f16*)(ws + 12648448);     // 32 MB
    f16* xmc16  = (f16*)(ws + 46202880);     // 16 MB: u (f16); pass2 writes y16 IN PLACE here
    float* xmcf = (float*)(ws + 62980096);   // 32 MB: traw (8192x768 f32 = 25.2 MB)
    float* xdbl = (float*)(ws + 96534528);   // 4 MB
    f16* dt16   = (f16*)(ws + 100728832);    // 512 KB
    f16* delta16 = (f16*)(ws + 101253120);   // 16 MB (f16 delta)

    // scan scratch: hloc (16.8 MB) lives in d_out (25.2 MB, only written by final LNs)
    float* hloc     = (float*)d_out;
    float* sumdelta = (float*)h16;           // 1 MB over dead h16 region

    f16* hm16 = h16;
    f16* y16 = xmc16;                        // in-place over u
    float* traw = xmcf;                      // ld 768
    float* out0 = (float*)d_out;
    float* out1 = out0 + (size_t)NROWS * DMODEL;

    // 1. LN(x) -> h16  +  weight conversions (fused)
    prep<<<NROWS / 4 + 1024, 256, 0, stream>>>(x, norm_w, norm_b, h16,
                                               in_proj_w, x_proj_w, dt_proj_w,
                                               mix_out_w, match_w, geom_w, wip);
    // 2. xz = h @ in_proj^T
    gemm_xwt<1><<<dim3(16, 64), 256, 0, stream>>>(h16, wip, xz16, 512, 2048, nullptr, nullptr);
    // 3. conv + silu -> u (f16)
    conv_silu<<<NROWS * DINNER / 8 / 256, 256, 0, stream>>>(xz16, conv_w, conv_b, xmc16);
    // 4. x_dbl = xm @ x_proj^T (f32 ld128) + dt16 fused
    gemm_xwt<3><<<dim3(1, 64), 256, 0, stream>>>(xmc16, wxp, xdbl, 1024, 128, nullptr, dt16);
    // 5. delta16 = softplus(dt @ dt_proj^T + b)  (f16 out)
    gemm_xwt<2><<<dim3(8, 64), 256, 0, stream>>>(dt16, wdt, delta16, 32, 1024, dt_proj_b, nullptr);
    // 6. chunked selective scan
    scan_pass1<<<NB * NCHUNK * 4, 256, 0, stream>>>(delta16, xmc16, xdbl, A_log, hloc, sumdelta);
    scan_combine<<<NB * DINNER * NSTATE / 256, 256, 0, stream>>>(hloc, sumdelta, A_log);
    scan_pass2<<<NB * NCHUNK * 4, 256, 0, stream>>>(delta16, xmc16, xdbl, A_log, Dvec, hloc, xz16, y16);
    // 7. hm = y @ mix_out^T
    gemm_xwt<1><<<dim3(4, 64), 256, 0, stream>>>(y16, wmo, hm16, 1024, 512, nullptr, nullptr);
    // 8. match+geom fused GEMM (N=768, contiguous weights)
    gemm_xwt<0><<<dim3(6, 64), 256, 0, stream>>>(hm16, wma, traw, 512, 768, nullptr, nullptr);
    // 9. fused output layernorms (d_out; hloc dead by now)
    ln_outputs<<<NROWS / 2, 256, 0, stream>>>(x, traw, match_b, geom_b,
                                              normm_w, normm_b, normg_w, normg_b, out0, out1);
}